// Round 5
// baseline (1740.008 us; speedup 1.0000x reference)
//
#include <hip/hip_runtime.h>
#include <stdint.h>

// Problem constants (fixed by setup_inputs)
#define PN     512
#define NFREE  50000
#define NCND   100000
#define NNODE  100512
#define NEDGE  300000
#define KK     10
#define NLOOP  5
#define EPSV   1e-5f

#define GRID   128
#define NCELL  (GRID*GRID)

#define HSIZE  (1u<<19)
#define HMASK  (HSIZE-1)
#define E0CAP  4096
#define EMPTYK 0xFFFFFFFFFFFFFFFFull

// workspace layout (bytes) — total ~7.4 MB
#define OFF_HASH    ((size_t)0)
#define OFF_CPOS    (OFF_HASH    + (size_t)HSIZE*8)
#define OFF_CSQ     (OFF_CPOS    + 800000)
#define OFF_SCND    (OFF_CSQ     + 400000)               // float4/cand, cell-sorted
#define OFF_CSTART  (OFF_SCND    + 1600000)              // NCELL+1 ints
#define OFF_COFS    (OFF_CSTART  + 65600)
#define OFF_MNMX    (OFF_COFS    + 65600)
#define OFF_SUMC    (OFF_MNMX    + 64)
#define OFF_SUMC2   (OFF_SUMC    + 128)
#define OFF_MEAN    (OFF_SUMC2   + 128)
#define OFF_RSTD    (OFF_MEAN    + 128)
#define OFF_WCU     (OFF_RSTD    + 128)
#define OFF_WCV     (OFF_WCU     + 4096)
#define OFF_BU      (OFF_WCV     + 4096)
#define OFF_BV      (OFF_BU      + 128)
#define OFF_CPATH   (OFF_BV      + 128)
#define OFF_CFREE   (OFF_CPATH   + 128)
#define OFF_CCOL    (OFF_CFREE   + 128)
#define OFF_PATH    (OFF_CCOL    + 128)
#define OFF_UPATH   (OFF_PATH    + 4096)
#define OFF_VDST    (OFF_UPATH   + 65536)
#define OFF_SBUF    (OFF_VDST    + 65536)
#define OFF_E0S     (OFF_SBUF    + 65536)
#define OFF_E0D     (OFF_E0S     + (size_t)E0CAP*4)
#define OFF_DEG0    (OFF_E0D     + (size_t)E0CAP*4)
#define OFF_E0C     (OFF_DEG0    + 2048)
#define OFF_KSRC    (OFF_E0C     + 64)
#define OFF_KKEEP   (OFF_KSRC    + (size_t)PN*KK*4)
#define OFF_E0START (OFF_KKEEP   + (size_t)PN*KK*4)      // 513 ints (pad 2112)
#define OFF_E0OFS   (OFF_E0START + 2112)                 // 512 ints
#define OFF_E0CSRS  (OFF_E0OFS   + 2048)                 // E0CAP ints

#define WS_F(o)  ((float*)(ws + (o)))
#define WS_I(o)  ((int*)(ws + (o)))
#define WS_U(o)  ((unsigned*)(ws + (o)))
#define WS_H(o)  ((unsigned long long*)(ws + (o)))

__device__ __forceinline__ bool lexless(float da, int ia, float db, int ib) {
  return (da < db) || (da == db && ia < ib);
}

__device__ __forceinline__ uint32_t hslot(unsigned long long key) {
  return (uint32_t)((key * 0x9E3779B97F4A7C15ull) >> 40) & HMASK;
}

// monotone float<->uint order encoding (for atomicMin/Max on floats)
__device__ __forceinline__ unsigned encf(float f) {
  unsigned u = __float_as_uint(f);
  return (u & 0x80000000u) ? ~u : (u | 0x80000000u);
}
__device__ __forceinline__ float decf(unsigned u) {
  return (u & 0x80000000u) ? __uint_as_float(u & 0x7FFFFFFFu) : __uint_as_float(~u);
}

#define INSERT10(d2v, jv)                                                  \
  if (lexless((d2v), (jv), bd[9], bi[9])) {                                \
    bool placed = false;                                                   \
    _Pragma("unroll")                                                      \
    for (int k = 9; k > 0; k--) {                                          \
      bool shift = !placed && lexless((d2v), (jv), bd[k-1], bi[k-1]);      \
      bool here  = !placed && !shift;                                      \
      if (here)       { bd[k] = (d2v); bi[k] = (jv); placed = true; }      \
      else if (shift) { bd[k] = bd[k-1]; bi[k] = bi[k-1]; }                \
    }                                                                      \
    if (!placed) { bd[0] = (d2v); bi[0] = (jv); }                          \
  }

// ---------------- setup kernels (once per launch) ----------------

__global__ __launch_bounds__(256) void k_init(char* __restrict__ ws,
                                              const float* __restrict__ path_in) {
  unsigned i = blockIdx.x * 256u + threadIdx.x;       // grid = HSIZE/256
  WS_H(OFF_HASH)[i] = EMPTYK;
  if (i < NCELL+1) WS_I(OFF_CSTART)[i] = 0;
  if (i < 1024) WS_F(OFF_PATH)[i] = path_in[i];
  if (i < 512)  WS_I(OFF_DEG0)[i] = 0;
  if (i < 32) { WS_F(OFF_SUMC)[i] = 0.f; WS_F(OFF_SUMC2)[i] = 0.f; }
  if (i < 4)  WS_U(OFF_MNMX)[i] = (i & 1) ? 0u : 0xFFFFFFFFu;
  if (i == 0)   *WS_I(OFF_E0C) = 0;
}

// candidate positions, norms, BN partial sums, bbox min/max
__global__ __launch_bounds__(256) void k_cand(char* __restrict__ ws,
    const float* __restrict__ freep, const float* __restrict__ collp,
    const float* __restrict__ ncw1, const float* __restrict__ ncb1) {
  __shared__ float ls[64];
  __shared__ unsigned mm[4];
  int tid = threadIdx.x;
  if (tid < 64) ls[tid] = 0.f;
  if (tid < 4)  mm[tid] = (tid & 1) ? 0u : 0xFFFFFFFFu;
  __syncthreads();
  int j = blockIdx.x * 256 + tid;
  float c0 = 0.f, c1 = 0.f;
  bool valid = (j < NCND);
  if (valid) {
    if (j < NFREE) { c0 = freep[2*j];          c1 = freep[2*j+1]; }
    else           { c0 = collp[2*(j-NFREE)];  c1 = collp[2*(j-NFREE)+1]; }
    WS_F(OFF_CPOS)[2*j] = c0; WS_F(OFF_CPOS)[2*j+1] = c1;
    WS_F(OFF_CSQ)[j] = c0*c0 + c1*c1;
    atomicMin(&mm[0], encf(c0)); atomicMax(&mm[1], encf(c0));
    atomicMin(&mm[2], encf(c1)); atomicMax(&mm[3], encf(c1));
  }
  for (int ff = 0; ff < 32; ff++) {
    int f = (tid + ff) & 31;
    if (valid) {
      float cls = (j < NFREE) ? (ncw1[96+f] + ncb1[f]) : (ncw1[128+f] + ncb1[f]);
      float h = fmaf(c1, ncw1[32+f], fmaf(c0, ncw1[f], cls));
      atomicAdd(&ls[f], h);
      atomicAdd(&ls[32+f], h*h);
    }
  }
  __syncthreads();
  if (tid < 32) {
    atomicAdd(&WS_F(OFF_SUMC)[tid],  ls[tid]);
    atomicAdd(&WS_F(OFF_SUMC2)[tid], ls[32+tid]);
  }
  if (tid < 4) {
    if (tid & 1) atomicMax(&WS_U(OFF_MNMX)[tid], mm[tid]);
    else         atomicMin(&WS_U(OFF_MNMX)[tid], mm[tid]);
  }
}

// combined weights: Wcu = ncW2·(W1a+W1b), Wcv = ncW2·(W1c−W1a), biases, class consts
__global__ __launch_bounds__(1024) void k_wprep(char* __restrict__ ws,
    const float* __restrict__ m0w1, const float* __restrict__ m0b1,
    const float* __restrict__ ncw1, const float* __restrict__ ncb1,
    const float* __restrict__ ncw2, const float* __restrict__ ncb2) {
  __shared__ float Wu[1024], Wv[1024];
  int tid = threadIdx.x, k = tid >> 5, g = tid & 31;
  float a = m0w1[k*32+g], b = m0w1[(k+32)*32+g], c = m0w1[(k+64)*32+g];
  Wu[tid] = a + b;  Wv[tid] = c - a;
  __syncthreads();
  float au = 0.f, av = 0.f;
  #pragma unroll
  for (int f = 0; f < 32; f++) {
    float w2 = ncw2[k*32+f];
    au = fmaf(w2, Wu[f*32+g], au);
    av = fmaf(w2, Wv[f*32+g], av);
  }
  WS_F(OFF_WCU)[tid] = au;  WS_F(OFF_WCV)[tid] = av;
  if (tid < 32) {
    float bu = 0.f, bv = 0.f;
    #pragma unroll
    for (int f = 0; f < 32; f++) {
      bu = fmaf(ncb2[f], Wu[f*32+tid], bu);
      bv = fmaf(ncb2[f], Wv[f*32+tid], bv);
    }
    WS_F(OFF_BU)[tid] = bu;
    WS_F(OFF_BV)[tid] = bv + m0b1[tid];
    WS_F(OFF_CPATH)[tid] = ncw1[64+tid]  + ncb1[tid];
    WS_F(OFF_CFREE)[tid] = ncw1[96+tid]  + ncb1[tid];
    WS_F(OFF_CCOL)[tid]  = ncw1[128+tid] + ncb1[tid];
  }
}

// hash-insert fixed edges (dedupe); compact kept edges with dst<PN; deg0 histogram
__global__ __launch_bounds__(256) void k_edges(char* __restrict__ ws,
                                               const int* __restrict__ ei) {
  int e = blockIdx.x * 256 + threadIdx.x;
  if (e >= NEDGE) return;
  int src = ei[e], dst = ei[NEDGE + e];
  unsigned long long key = (unsigned long long)src * NNODE + (unsigned long long)dst;
  unsigned long long* hash = WS_H(OFF_HASH);
  uint32_t slot = hslot(key);
  bool win = false;
  for (;;) {
    unsigned long long prev = atomicCAS(&hash[slot], EMPTYK, key);
    if (prev == EMPTYK) { win = true; break; }
    if (prev == key)    { break; }
    slot = (slot + 1) & HMASK;
  }
  if (win && dst < PN) {
    int pos = atomicAdd(WS_I(OFF_E0C), 1);
    if (pos < E0CAP) {
      WS_I(OFF_E0S)[pos] = src;
      WS_I(OFF_E0D)[pos] = dst;
      atomicAdd(&WS_I(OFF_DEG0)[dst], 1);
    }
  }
}

// build per-dst CSR of fixed edges with dst<PN (~1528 entries, avg 3/dst)
__global__ __launch_bounds__(256) void k_csr(char* __restrict__ ws) {
  __shared__ int sc[512];
  int tid = threadIdx.x;
  sc[tid]     = WS_I(OFF_DEG0)[tid];
  sc[256+tid] = WS_I(OFF_DEG0)[256+tid];
  __syncthreads();
  if (tid == 0) {                     // one-time serial scan of 512 — fine
    int run = 0;
    for (int i = 0; i < 512; i++) { int c = sc[i]; sc[i] = run; run += c; }
    WS_I(OFF_E0START)[512] = run;
  }
  __syncthreads();
  WS_I(OFF_E0START)[tid]     = sc[tid];
  WS_I(OFF_E0START)[256+tid] = sc[256+tid];
  WS_I(OFF_E0OFS)[tid]       = sc[tid];
  WS_I(OFF_E0OFS)[256+tid]   = sc[256+tid];
  __syncthreads();
  int n = *WS_I(OFF_E0C); if (n > E0CAP) n = E0CAP;
  for (int e = tid; e < n; e += 256) {
    int dst = WS_I(OFF_E0D)[e];
    int pos = atomicAdd(&WS_I(OFF_E0OFS)[dst], 1);
    WS_I(OFF_E0CSRS)[pos] = WS_I(OFF_E0S)[e];
  }
}

// grid histogram over candidate cells
__global__ __launch_bounds__(256) void k_hist(char* __restrict__ ws) {
  int j = blockIdx.x * 256 + threadIdx.x;
  if (j >= NCND) return;
  const unsigned* mnmx = WS_U(OFF_MNMX);
  float xmin = decf(mnmx[0]), xmax = decf(mnmx[1]);
  float ymin = decf(mnmx[2]), ymax = decf(mnmx[3]);
  float ivx = (float)GRID / ((xmax - xmin) * 1.000001f + 1e-30f);
  float ivy = (float)GRID / ((ymax - ymin) * 1.000001f + 1e-30f);
  float c0 = WS_F(OFF_CPOS)[2*j], c1 = WS_F(OFF_CPOS)[2*j+1];
  int cx = min(GRID-1, max(0, (int)((c0 - xmin) * ivx)));
  int cy = min(GRID-1, max(0, (int)((c1 - ymin) * ivy)));
  atomicAdd(&WS_I(OFF_CSTART)[cy*GRID + cx], 1);
}

// exclusive scan of cell counts (single block)
__global__ __launch_bounds__(256) void k_scan(char* __restrict__ ws) {
  __shared__ int part[256];
  int tid = threadIdx.x;
  int* cnt = WS_I(OFF_CSTART);
  int base = tid * (NCELL/256);
  int sum = 0;
  for (int k = 0; k < NCELL/256; k++) sum += cnt[base+k];
  part[tid] = sum;
  __syncthreads();
  for (int off = 1; off < 256; off <<= 1) {
    int t = (tid >= off) ? part[tid - off] : 0;
    __syncthreads();
    part[tid] += t;
    __syncthreads();
  }
  int run = part[tid] - sum;
  for (int k = 0; k < NCELL/256; k++) {
    int c = cnt[base+k];
    cnt[base+k] = run;
    WS_I(OFF_COFS)[base+k] = run;
    run += c;
  }
  if (tid == 255) cnt[NCELL] = run;
}

// scatter candidates into cell-sorted float4 array (x, y, |c|^2, idx)
__global__ __launch_bounds__(256) void k_scatter(char* __restrict__ ws) {
  int j = blockIdx.x * 256 + threadIdx.x;
  if (j >= NCND) return;
  const unsigned* mnmx = WS_U(OFF_MNMX);
  float xmin = decf(mnmx[0]), xmax = decf(mnmx[1]);
  float ymin = decf(mnmx[2]), ymax = decf(mnmx[3]);
  float ivx = (float)GRID / ((xmax - xmin) * 1.000001f + 1e-30f);
  float ivy = (float)GRID / ((ymax - ymin) * 1.000001f + 1e-30f);
  float c0 = WS_F(OFF_CPOS)[2*j], c1 = WS_F(OFF_CPOS)[2*j+1];
  int cx = min(GRID-1, max(0, (int)((c0 - xmin) * ivx)));
  int cy = min(GRID-1, max(0, (int)((c1 - ymin) * ivy)));
  int pos = atomicAdd(&WS_I(OFF_COFS)[cy*GRID + cx], 1);
  ((float4*)(ws + OFF_SCND))[pos] =
      make_float4(c0, c1, WS_F(OFF_CSQ)[j], __int_as_float(j));
}

// ---------------- per-loop kernels ----------------

// non-destructive wave top-10 pop-merge: refreshes cur10d, lane r stores r-th idx
#define MERGEPOP() do {                                                    \
    float cd[10]; int ci[10];                                              \
    _Pragma("unroll")                                                      \
    for (int k = 0; k < 10; k++) { cd[k] = bd[k]; ci[k] = bi[k]; }         \
    _Pragma("unroll")                                                      \
    for (int r = 0; r < 10; r++) {                                         \
      float md = cd[0]; int mi = ci[0];                                    \
      _Pragma("unroll")                                                    \
      for (int off = 32; off >= 1; off >>= 1) {                            \
        float od = __shfl_xor(md, off);                                    \
        int   oi = __shfl_xor(mi, off);                                    \
        if (lexless(od, oi, md, mi)) { md = od; mi = oi; }                 \
      }                                                                    \
      bool win = (cd[0] == md) && (ci[0] == mi);                           \
      if (win) {                                                           \
        _Pragma("unroll")                                                  \
        for (int k = 0; k < 9; k++) { cd[k] = cd[k+1]; ci[k] = ci[k+1]; }  \
        cd[9] = 3.4e38f; ci[9] = 0x7FFFFFFF;                               \
      }                                                                    \
      if (lane == r) selIdx = mi;                                          \
      cur10d = md;                                                         \
    }                                                                      \
  } while (0)

// scan box rows [yA..yB] x cells [xA..xB]: each row is a CONTIGUOUS scnd span
// (cells row-major) — all 64 lanes stride one span (coalesced float4 loads).
#define SCAN_BOX(xA, xB, yA, yB) do {                                      \
    for (int _y = (yA); _y <= (yB); _y++) {                                \
      int _s = cst[_y*GRID + (xA)], _e = cst[_y*GRID + (xB) + 1];          \
      for (int _t = _s + lane; _t < _e; _t += 64) {                        \
        float4 _q = scnd[_t];                                              \
        float _d2 = (psq + _q.z) - 2.f * fmaf(p1, _q.y, p0 * _q.x);        \
        int _j = __float_as_int(_q.w);                                     \
        INSERT10(_d2, _j);                                                 \
      }                                                                    \
    }                                                                      \
  } while (0)

// blocks 0..127: one wave per path node — seed-box + exact-radius grid kNN +
// CSR dedup + KSRC/KKEEP.  block 128: BN stats + u/v + zero SBUF.
__global__ __launch_bounds__(256) void k_knng(char* __restrict__ ws,
    const float* __restrict__ ncw1, const float* __restrict__ gamma,
    const float* __restrict__ beta) {
  __shared__ float ps[128];
  int tid = threadIdx.x, b = blockIdx.x;
  float* pathb = WS_F(OFF_PATH);

  if (b < PN/4) {
    int lane = tid & 63, wave = tid >> 6;
    int node = (b << 2) + wave;
    const float4* scnd = (const float4*)(ws + OFF_SCND);
    const int* cst = WS_I(OFF_CSTART);
    const unsigned* mnmx = WS_U(OFF_MNMX);
    float xmin = decf(mnmx[0]), xmax = decf(mnmx[1]);
    float ymin = decf(mnmx[2]), ymax = decf(mnmx[3]);
    float spx = (xmax - xmin) * 1.000001f + 1e-30f;
    float spy = (ymax - ymin) * 1.000001f + 1e-30f;
    float ivx = (float)GRID / spx, ivy = (float)GRID / spy;
    float p0 = pathb[2*node], p1 = pathb[2*node+1];
    float psq = p0*p0 + p1*p1;
    int cx = min(GRID-1, max(0, (int)((p0 - xmin) * ivx)));
    int cy = min(GRID-1, max(0, (int)((p1 - ymin) * ivy)));

    // ---- phase A: grow square box (prefix-count only) until >= 10 pts ----
    int R = 1, xL, xR, yL, yR;
    for (;;) {
      xL = max(cx - R, 0); xR = min(cx + R, GRID-1);
      yL = max(cy - R, 0); yR = min(cy + R, GRID-1);
      int cnt = 0;
      for (int y = yL + lane; y <= yR; y += 64)
        cnt += cst[y*GRID + xR + 1] - cst[y*GRID + xL];
      #pragma unroll
      for (int off = 32; off >= 1; off >>= 1) cnt += __shfl_xor(cnt, off);
      if (cnt >= KK || R >= GRID) break;
      R <<= 1;
    }

    float bd[10]; int bi[10];
    #pragma unroll
    for (int k = 0; k < 10; k++) { bd[k] = 3.4e38f; bi[k] = 0x7FFFFFFF; }
    float cur10d = 3.4e38f;
    int selIdx = 0x7FFFFFFF;

    // ---- phase B: scan seed box -> d2_10 upper bound (exact within box) ----
    SCAN_BOX(xL, xR, yL, yR);
    MERGEPOP();

    // ---- phase C: exact pass over cells overlapping [p +- r] square ----
    // (unscanned => |dx|>r or |dy|>r => d2 > cur10d >= true d2_10 => cannot
    //  enter top-10 even via index tie-break; seed top-10 lie inside => >=10)
    float r = sqrtf(cur10d) * 1.000002f;
    int xL2 = min(GRID-1, max(0, (int)((p0 - r - xmin) * ivx)));
    int xR2 = min(GRID-1, max(0, (int)((p0 + r - xmin) * ivx)));
    int yL2 = min(GRID-1, max(0, (int)((p1 - r - ymin) * ivy)));
    int yR2 = min(GRID-1, max(0, (int)((p1 + r - ymin) * ivy)));
    #pragma unroll
    for (int k = 0; k < 10; k++) { bd[k] = 3.4e38f; bi[k] = 0x7FFFFFFF; }
    SCAN_BOX(xL2, xR2, yL2, yR2);
    MERGEPOP();

    // lanes 0..9 hold the rank-r neighbor; dedup vs fixed edges via tiny CSR
    if (lane < KK) {
      int srcg = selIdx + PN;
      int s = WS_I(OFF_E0START)[node], e = WS_I(OFF_E0START)[node+1];
      int keep = 1;
      for (int t = s; t < e; t++)
        if (WS_I(OFF_E0CSRS)[t] == srcg) { keep = 0; break; }
      WS_I(OFF_KSRC)[node*KK+lane]  = srcg;
      WS_I(OFF_KKEEP)[node*KK+lane] = keep;
    }
  } else {
    // ---- BN stats over path rows (cand part precomputed) ----
    if (tid < 64) ps[tid] = 0.f;
    __syncthreads();
    const float* cpath = WS_F(OFF_CPATH);
    for (int r = tid; r < PN; r += 256) {
      float p0 = pathb[2*r], p1 = pathb[2*r+1];
      for (int ff = 0; ff < 32; ff++) {
        int f = (tid + ff) & 31;
        float h = fmaf(p1, ncw1[32+f], fmaf(p0, ncw1[f], cpath[f]));
        atomicAdd(&ps[f], h);
        atomicAdd(&ps[32+f], h*h);
      }
    }
    __syncthreads();
    if (tid < 32) {
      float mean = (WS_F(OFF_SUMC)[tid]  + ps[tid])    * (1.f / NNODE);
      float ex2  = (WS_F(OFF_SUMC2)[tid] + ps[32+tid]) * (1.f / NNODE);
      float var  = ex2 - mean * mean;
      float rs   = 1.0f / sqrtf(var + EPSV);
      WS_F(OFF_MEAN)[tid] = mean; WS_F(OFF_RSTD)[tid] = rs;
      ps[64+tid] = mean; ps[96+tid] = rs;
    }
    __syncthreads();
    // ---- u/v for all 512 path nodes ----
    const float* wcu = WS_F(OFF_WCU); const float* wcv = WS_F(OFF_WCV);
    const float* bu  = WS_F(OFF_BU);  const float* bv  = WS_F(OFF_BV);
    for (int i = tid; i < PN; i += 256) {
      float p0 = pathb[2*i], p1 = pathb[2*i+1];
      float xn[32];
      #pragma unroll
      for (int f = 0; f < 32; f++) {
        float h = fmaf(p1, ncw1[32+f], fmaf(p0, ncw1[f], cpath[f]));
        float t = (h - ps[64+f]) * ps[96+f];
        t = fmaf(t, gamma[f], beta[f]);
        xn[f] = t > 0.f ? t : 0.f;
      }
      for (int f = 0; f < 32; f++) {
        float au = bu[f], av = bv[f];
        #pragma unroll
        for (int k = 0; k < 32; k++) {
          au = fmaf(xn[k], wcu[k*32+f], au);
          av = fmaf(xn[k], wcv[k*32+f], av);
        }
        WS_F(OFF_UPATH)[i*32+f] = au;
        WS_F(OFF_VDST)[i*32+f]  = av;
      }
    }
    for (int i = tid; i < PN*32; i += 256) WS_F(OFF_SBUF)[i] = 0.f;
  }
}

// per-edge: r = relu(u[src]+v[dst]) accumulated into S[dst]
__global__ __launch_bounds__(256) void k_loopB(char* __restrict__ ws,
    const float* __restrict__ ncw1, const float* __restrict__ gamma,
    const float* __restrict__ beta) {
  int t = blockIdx.x * 256 + threadIdx.x;
  int src, dst;
  if (t < PN*KK) {
    dst = t / KK;
    src = WS_I(OFF_KSRC)[t];
    if (!WS_I(OFF_KKEEP)[t]) return;
  } else {
    int e = t - PN*KK;
    if (e >= *WS_I(OFF_E0C)) return;
    src = WS_I(OFF_E0S)[e];
    dst = WS_I(OFF_E0D)[e];
  }
  float u[32];
  if (src < PN) {
    const float4* up4 = (const float4*)&WS_F(OFF_UPATH)[src*32];
    #pragma unroll
    for (int q = 0; q < 8; q++) {
      float4 w = up4[q];
      u[4*q] = w.x; u[4*q+1] = w.y; u[4*q+2] = w.z; u[4*q+3] = w.w;
    }
  } else {
    int j = src - PN;
    float c0 = WS_F(OFF_CPOS)[2*j], c1 = WS_F(OFF_CPOS)[2*j+1];
    const float* cls = (j < NFREE) ? WS_F(OFF_CFREE) : WS_F(OFF_CCOL);
    const float* mean = WS_F(OFF_MEAN); const float* rstd = WS_F(OFF_RSTD);
    float xn[32];
    #pragma unroll
    for (int f = 0; f < 32; f++) {
      float h = fmaf(c1, ncw1[32+f], fmaf(c0, ncw1[f], cls[f]));
      float tt = (h - mean[f]) * rstd[f];
      tt = fmaf(tt, gamma[f], beta[f]);
      xn[f] = tt > 0.f ? tt : 0.f;
    }
    const float* wcu = WS_F(OFF_WCU); const float* bu = WS_F(OFF_BU);
    for (int f = 0; f < 32; f++) {
      float au = bu[f];
      #pragma unroll
      for (int k = 0; k < 32; k++) au = fmaf(xn[k], wcu[k*32+f], au);
      u[f] = au;
    }
  }
  const float* vd = &WS_F(OFF_VDST)[dst*32];
  float* sb = &WS_F(OFF_SBUF)[dst*32];
  #pragma unroll
  for (int f = 0; f < 32; f++) {
    float r = u[f] + vd[f];
    if (r > 0.f) atomicAdd(&sb[f], r);
  }
}

// epilogue per path node: out -> mp1 -> h = x + g -> smooth -> path update + d_out
__global__ __launch_bounds__(256) void k_loopC(char* __restrict__ ws,
    const float* __restrict__ ncw1, const float* __restrict__ gamma,
    const float* __restrict__ beta, const float* __restrict__ ncw2,
    const float* __restrict__ ncb2, const float* __restrict__ m0w2,
    const float* __restrict__ m0b2, const float* __restrict__ m1w1,
    const float* __restrict__ m1b1, const float* __restrict__ m1w2,
    const float* __restrict__ m1b2, const float* __restrict__ snw,
    const float* __restrict__ snb, float* __restrict__ outp) {
  int i = blockIdx.x * 256 + threadIdx.x;
  if (i >= PN) return;
  float s[32];
  #pragma unroll
  for (int f = 0; f < 32; f++) s[f] = WS_F(OFF_SBUF)[i*32+f];
  int deg = WS_I(OFF_DEG0)[i];
  #pragma unroll
  for (int k = 0; k < KK; k++) deg += WS_I(OFF_KKEEP)[i*KK+k];
  float fdeg = (float)deg;

  float o[32];
  for (int f = 0; f < 32; f++) {
    float acc = 0.f;
    #pragma unroll
    for (int k = 0; k < 32; k++) acc = fmaf(s[k], m0w2[k*32+f], acc);
    o[f] = fmaf(fdeg, m0b2[f], acc);
  }
  float t[32];
  for (int f = 0; f < 32; f++) {
    float acc = m1b1[f];
    #pragma unroll
    for (int k = 0; k < 32; k++) acc = fmaf(o[k], m1w1[k*32+f], acc);
    t[f] = acc > 0.f ? acc : 0.f;
  }
  float g[32];
  for (int f = 0; f < 32; f++) {
    float acc = m1b2[f];
    #pragma unroll
    for (int k = 0; k < 32; k++) acc = fmaf(t[k], m1w2[k*32+f], acc);
    g[f] = acc;
  }
  float p0 = WS_F(OFF_PATH)[2*i], p1 = WS_F(OFF_PATH)[2*i+1];
  const float* cpath = WS_F(OFF_CPATH);
  const float* mean = WS_F(OFF_MEAN); const float* rstd = WS_F(OFF_RSTD);
  float xn[32];
  #pragma unroll
  for (int f = 0; f < 32; f++) {
    float h = fmaf(p1, ncw1[32+f], fmaf(p0, ncw1[f], cpath[f]));
    float tt = (h - mean[f]) * rstd[f];
    tt = fmaf(tt, gamma[f], beta[f]);
    xn[f] = tt > 0.f ? tt : 0.f;
  }
  float sm0 = snb[0], sm1 = snb[1];
  for (int f = 0; f < 32; f++) {
    float acc = ncb2[f];
    #pragma unroll
    for (int k = 0; k < 32; k++) acc = fmaf(xn[k], ncw2[k*32+f], acc);
    float h = acc + g[f];
    sm0 = fmaf(h, snw[2*f],   sm0);
    sm1 = fmaf(h, snw[2*f+1], sm1);
  }
  float np0, np1;
  if (i == 0 || i == PN-1) { np0 = p0; np1 = p1; }
  else                     { np0 = sm0; np1 = sm1; }
  WS_F(OFF_PATH)[2*i]   = np0;
  WS_F(OFF_PATH)[2*i+1] = np1;
  outp[2*i]   = np0;
  outp[2*i+1] = np1;
}

// ---------------- host launch ----------------

extern "C" void kernel_launch(void* const* d_in, const int* in_sizes, int n_in,
                              void* d_out, int out_size, void* d_ws, size_t ws_size,
                              hipStream_t stream) {
  const float* path  = (const float*)d_in[0];
  const float* freep = (const float*)d_in[1];
  const float* collp = (const float*)d_in[2];
  const int*   ei    = (const int*)d_in[4];
  const float* ncw1  = (const float*)d_in[6];
  const float* ncb1  = (const float*)d_in[7];
  const float* gamma = (const float*)d_in[8];
  const float* beta  = (const float*)d_in[9];
  const float* ncw2  = (const float*)d_in[10];
  const float* ncb2  = (const float*)d_in[11];
  const float* m0w1  = (const float*)d_in[12];
  const float* m0b1  = (const float*)d_in[13];
  const float* m0w2  = (const float*)d_in[14];
  const float* m0b2  = (const float*)d_in[15];
  const float* m1w1  = (const float*)d_in[16];
  const float* m1b1  = (const float*)d_in[17];
  const float* m1w2  = (const float*)d_in[18];
  const float* m1b2  = (const float*)d_in[19];
  const float* snw   = (const float*)d_in[20];
  const float* snb   = (const float*)d_in[21];
  char* ws = (char*)d_ws;

  k_init   <<<HSIZE/256, 256, 0, stream>>>(ws, path);
  k_cand   <<<(NCND+255)/256, 256, 0, stream>>>(ws, freep, collp, ncw1, ncb1);
  k_wprep  <<<1, 1024, 0, stream>>>(ws, m0w1, m0b1, ncw1, ncb1, ncw2, ncb2);
  k_edges  <<<(NEDGE+255)/256, 256, 0, stream>>>(ws, ei);
  k_csr    <<<1, 256, 0, stream>>>(ws);
  k_hist   <<<(NCND+255)/256, 256, 0, stream>>>(ws);
  k_scan   <<<1, 256, 0, stream>>>(ws);
  k_scatter<<<(NCND+255)/256, 256, 0, stream>>>(ws);

  for (int l = 0; l < NLOOP; l++) {
    k_knng <<<PN/4 + 1, 256, 0, stream>>>(ws, ncw1, gamma, beta);
    k_loopB<<<(PN*KK + E0CAP + 255)/256, 256, 0, stream>>>(ws, ncw1, gamma, beta);
    k_loopC<<<2, 256, 0, stream>>>(ws, ncw1, gamma, beta, ncw2, ncb2,
                                   m0w2, m0b2, m1w1, m1b1, m1w2, m1b2,
                                   snw, snb, (float*)d_out);
  }
}

// Round 6
// 651.035 us; speedup vs baseline: 2.6727x; 2.6727x over previous
//
#include <hip/hip_runtime.h>
#include <stdint.h>

// Problem constants (fixed by setup_inputs)
#define PN     512
#define NFREE  50000
#define NCND   100000
#define NNODE  100512
#define NEDGE  300000
#define KK     10
#define NLOOP  5
#define EPSV   1e-5f

#define GRID   128
#define NCELL  (GRID*GRID)

#define HSIZE  (1u<<19)
#define HMASK  (HSIZE-1)
#define E0CAP  4096
#define EMPTYK 0xFFFFFFFFFFFFFFFFull

// workspace layout (bytes) — total ~7.4 MB
#define OFF_HASH    ((size_t)0)
#define OFF_CPOS    (OFF_HASH    + (size_t)HSIZE*8)
#define OFF_CSQ     (OFF_CPOS    + 800000)
#define OFF_SCND    (OFF_CSQ     + 400000)               // float4/cand, cell-sorted
#define OFF_CSTART  (OFF_SCND    + 1600000)              // NCELL+1 ints
#define OFF_COFS    (OFF_CSTART  + 65600)
#define OFF_MNMX    (OFF_COFS    + 65600)
#define OFF_SUMC    (OFF_MNMX    + 64)
#define OFF_SUMC2   (OFF_SUMC    + 128)
#define OFF_MEAN    (OFF_SUMC2   + 128)
#define OFF_RSTD    (OFF_MEAN    + 128)
#define OFF_WCU     (OFF_RSTD    + 128)
#define OFF_WCV     (OFF_WCU     + 4096)
#define OFF_BU      (OFF_WCV     + 4096)
#define OFF_BV      (OFF_BU      + 128)
#define OFF_CPATH   (OFF_BV      + 128)
#define OFF_CFREE   (OFF_CPATH   + 128)
#define OFF_CCOL    (OFF_CFREE   + 128)
#define OFF_PATH    (OFF_CCOL    + 128)
#define OFF_UPATH   (OFF_PATH    + 4096)
#define OFF_VDST    (OFF_UPATH   + 65536)
#define OFF_SBUF    (OFF_VDST    + 65536)
#define OFF_E0S     (OFF_SBUF    + 65536)
#define OFF_E0D     (OFF_E0S     + (size_t)E0CAP*4)
#define OFF_DEG0    (OFF_E0D     + (size_t)E0CAP*4)
#define OFF_E0C     (OFF_DEG0    + 2048)
#define OFF_KSRC    (OFF_E0C     + 64)
#define OFF_KKEEP   (OFF_KSRC    + (size_t)PN*KK*4)
#define OFF_E0START (OFF_KKEEP   + (size_t)PN*KK*4)      // 513 ints (pad 2112)
#define OFF_E0OFS   (OFF_E0START + 2112)                 // 512 ints
#define OFF_E0CSRS  (OFF_E0OFS   + 2048)                 // E0CAP ints

#define WS_F(o)  ((float*)(ws + (o)))
#define WS_I(o)  ((int*)(ws + (o)))
#define WS_U(o)  ((unsigned*)(ws + (o)))
#define WS_H(o)  ((unsigned long long*)(ws + (o)))

__device__ __forceinline__ bool lexless(float da, int ia, float db, int ib) {
  return (da < db) || (da == db && ia < ib);
}

__device__ __forceinline__ uint32_t hslot(unsigned long long key) {
  return (uint32_t)((key * 0x9E3779B97F4A7C15ull) >> 40) & HMASK;
}

// monotone float<->uint order encoding (for atomicMin/Max on floats)
__device__ __forceinline__ unsigned encf(float f) {
  unsigned u = __float_as_uint(f);
  return (u & 0x80000000u) ? ~u : (u | 0x80000000u);
}
__device__ __forceinline__ float decf(unsigned u) {
  return (u & 0x80000000u) ? __uint_as_float(u & 0x7FFFFFFFu) : __uint_as_float(~u);
}

#define INSERT10(d2v, jv)                                                  \
  if (lexless((d2v), (jv), bd[9], bi[9])) {                                \
    bool placed = false;                                                   \
    _Pragma("unroll")                                                      \
    for (int k = 9; k > 0; k--) {                                          \
      bool shift = !placed && lexless((d2v), (jv), bd[k-1], bi[k-1]);      \
      bool here  = !placed && !shift;                                      \
      if (here)       { bd[k] = (d2v); bi[k] = (jv); placed = true; }      \
      else if (shift) { bd[k] = bd[k-1]; bi[k] = bi[k-1]; }                \
    }                                                                      \
    if (!placed) { bd[0] = (d2v); bi[0] = (jv); }                          \
  }

// ---------------- setup kernels (once per launch) ----------------

__global__ __launch_bounds__(256) void k_init(char* __restrict__ ws,
                                              const float* __restrict__ path_in) {
  unsigned i = blockIdx.x * 256u + threadIdx.x;       // grid = HSIZE/256
  WS_H(OFF_HASH)[i] = EMPTYK;
  if (i < NCELL+1) WS_I(OFF_CSTART)[i] = 0;
  if (i < 1024) WS_F(OFF_PATH)[i] = path_in[i];
  if (i < 512)  WS_I(OFF_DEG0)[i] = 0;
  if (i < 32) { WS_F(OFF_SUMC)[i] = 0.f; WS_F(OFF_SUMC2)[i] = 0.f; }
  if (i < 4)  WS_U(OFF_MNMX)[i] = (i & 1) ? 0u : 0xFFFFFFFFu;
  if (i == 0)   *WS_I(OFF_E0C) = 0;
}

// candidate positions, norms, BN partial sums, bbox min/max
__global__ __launch_bounds__(256) void k_cand(char* __restrict__ ws,
    const float* __restrict__ freep, const float* __restrict__ collp,
    const float* __restrict__ ncw1, const float* __restrict__ ncb1) {
  __shared__ float ls[64];
  __shared__ unsigned mm[4];
  int tid = threadIdx.x;
  if (tid < 64) ls[tid] = 0.f;
  if (tid < 4)  mm[tid] = (tid & 1) ? 0u : 0xFFFFFFFFu;
  __syncthreads();
  int j = blockIdx.x * 256 + tid;
  float c0 = 0.f, c1 = 0.f;
  bool valid = (j < NCND);
  if (valid) {
    if (j < NFREE) { c0 = freep[2*j];          c1 = freep[2*j+1]; }
    else           { c0 = collp[2*(j-NFREE)];  c1 = collp[2*(j-NFREE)+1]; }
    WS_F(OFF_CPOS)[2*j] = c0; WS_F(OFF_CPOS)[2*j+1] = c1;
    WS_F(OFF_CSQ)[j] = c0*c0 + c1*c1;
    atomicMin(&mm[0], encf(c0)); atomicMax(&mm[1], encf(c0));
    atomicMin(&mm[2], encf(c1)); atomicMax(&mm[3], encf(c1));
  }
  for (int ff = 0; ff < 32; ff++) {
    int f = (tid + ff) & 31;
    if (valid) {
      float cls = (j < NFREE) ? (ncw1[96+f] + ncb1[f]) : (ncw1[128+f] + ncb1[f]);
      float h = fmaf(c1, ncw1[32+f], fmaf(c0, ncw1[f], cls));
      atomicAdd(&ls[f], h);
      atomicAdd(&ls[32+f], h*h);
    }
  }
  __syncthreads();
  if (tid < 32) {
    atomicAdd(&WS_F(OFF_SUMC)[tid],  ls[tid]);
    atomicAdd(&WS_F(OFF_SUMC2)[tid], ls[32+tid]);
  }
  if (tid < 4) {
    if (tid & 1) atomicMax(&WS_U(OFF_MNMX)[tid], mm[tid]);
    else         atomicMin(&WS_U(OFF_MNMX)[tid], mm[tid]);
  }
}

// combined weights: Wcu = ncW2·(W1a+W1b), Wcv = ncW2·(W1c−W1a), biases, class consts
__global__ __launch_bounds__(1024) void k_wprep(char* __restrict__ ws,
    const float* __restrict__ m0w1, const float* __restrict__ m0b1,
    const float* __restrict__ ncw1, const float* __restrict__ ncb1,
    const float* __restrict__ ncw2, const float* __restrict__ ncb2) {
  __shared__ float Wu[1024], Wv[1024];
  int tid = threadIdx.x, k = tid >> 5, g = tid & 31;
  float a = m0w1[k*32+g], b = m0w1[(k+32)*32+g], c = m0w1[(k+64)*32+g];
  Wu[tid] = a + b;  Wv[tid] = c - a;
  __syncthreads();
  float au = 0.f, av = 0.f;
  #pragma unroll
  for (int f = 0; f < 32; f++) {
    float w2 = ncw2[k*32+f];
    au = fmaf(w2, Wu[f*32+g], au);
    av = fmaf(w2, Wv[f*32+g], av);
  }
  WS_F(OFF_WCU)[tid] = au;  WS_F(OFF_WCV)[tid] = av;
  if (tid < 32) {
    float bu = 0.f, bv = 0.f;
    #pragma unroll
    for (int f = 0; f < 32; f++) {
      bu = fmaf(ncb2[f], Wu[f*32+tid], bu);
      bv = fmaf(ncb2[f], Wv[f*32+tid], bv);
    }
    WS_F(OFF_BU)[tid] = bu;
    WS_F(OFF_BV)[tid] = bv + m0b1[tid];
    WS_F(OFF_CPATH)[tid] = ncw1[64+tid]  + ncb1[tid];
    WS_F(OFF_CFREE)[tid] = ncw1[96+tid]  + ncb1[tid];
    WS_F(OFF_CCOL)[tid]  = ncw1[128+tid] + ncb1[tid];
  }
}

// hash-insert fixed edges (dedupe); compact kept edges with dst<PN; deg0 histogram
__global__ __launch_bounds__(256) void k_edges(char* __restrict__ ws,
                                               const int* __restrict__ ei) {
  int e = blockIdx.x * 256 + threadIdx.x;
  if (e >= NEDGE) return;
  int src = ei[e], dst = ei[NEDGE + e];
  unsigned long long key = (unsigned long long)src * NNODE + (unsigned long long)dst;
  unsigned long long* hash = WS_H(OFF_HASH);
  uint32_t slot = hslot(key);
  bool win = false;
  for (;;) {
    unsigned long long prev = atomicCAS(&hash[slot], EMPTYK, key);
    if (prev == EMPTYK) { win = true; break; }
    if (prev == key)    { break; }
    slot = (slot + 1) & HMASK;
  }
  if (win && dst < PN) {
    int pos = atomicAdd(WS_I(OFF_E0C), 1);
    if (pos < E0CAP) {
      WS_I(OFF_E0S)[pos] = src;
      WS_I(OFF_E0D)[pos] = dst;
      atomicAdd(&WS_I(OFF_DEG0)[dst], 1);
    }
  }
}

// build per-dst CSR of fixed edges with dst<PN (~1528 entries, avg 3/dst)
__global__ __launch_bounds__(256) void k_csr(char* __restrict__ ws) {
  __shared__ int sc[512];
  int tid = threadIdx.x;
  sc[tid]     = WS_I(OFF_DEG0)[tid];
  sc[256+tid] = WS_I(OFF_DEG0)[256+tid];
  __syncthreads();
  if (tid == 0) {                     // one-time serial scan of 512 — fine
    int run = 0;
    for (int i = 0; i < 512; i++) { int c = sc[i]; sc[i] = run; run += c; }
    WS_I(OFF_E0START)[512] = run;
  }
  __syncthreads();
  WS_I(OFF_E0START)[tid]     = sc[tid];
  WS_I(OFF_E0START)[256+tid] = sc[256+tid];
  WS_I(OFF_E0OFS)[tid]       = sc[tid];
  WS_I(OFF_E0OFS)[256+tid]   = sc[256+tid];
  __syncthreads();
  int n = *WS_I(OFF_E0C); if (n > E0CAP) n = E0CAP;
  for (int e = tid; e < n; e += 256) {
    int dst = WS_I(OFF_E0D)[e];
    int pos = atomicAdd(&WS_I(OFF_E0OFS)[dst], 1);
    WS_I(OFF_E0CSRS)[pos] = WS_I(OFF_E0S)[e];
  }
}

// grid histogram over candidate cells
__global__ __launch_bounds__(256) void k_hist(char* __restrict__ ws) {
  int j = blockIdx.x * 256 + threadIdx.x;
  if (j >= NCND) return;
  const unsigned* mnmx = WS_U(OFF_MNMX);
  float xmin = decf(mnmx[0]), xmax = decf(mnmx[1]);
  float ymin = decf(mnmx[2]), ymax = decf(mnmx[3]);
  float ivx = (float)GRID / ((xmax - xmin) * 1.000001f + 1e-30f);
  float ivy = (float)GRID / ((ymax - ymin) * 1.000001f + 1e-30f);
  float c0 = WS_F(OFF_CPOS)[2*j], c1 = WS_F(OFF_CPOS)[2*j+1];
  int cx = min(GRID-1, max(0, (int)((c0 - xmin) * ivx)));
  int cy = min(GRID-1, max(0, (int)((c1 - ymin) * ivy)));
  atomicAdd(&WS_I(OFF_CSTART)[cy*GRID + cx], 1);
}

// exclusive scan of cell counts (single block)
__global__ __launch_bounds__(256) void k_scan(char* __restrict__ ws) {
  __shared__ int part[256];
  int tid = threadIdx.x;
  int* cnt = WS_I(OFF_CSTART);
  int base = tid * (NCELL/256);
  int sum = 0;
  for (int k = 0; k < NCELL/256; k++) sum += cnt[base+k];
  part[tid] = sum;
  __syncthreads();
  for (int off = 1; off < 256; off <<= 1) {
    int t = (tid >= off) ? part[tid - off] : 0;
    __syncthreads();
    part[tid] += t;
    __syncthreads();
  }
  int run = part[tid] - sum;
  for (int k = 0; k < NCELL/256; k++) {
    int c = cnt[base+k];
    cnt[base+k] = run;
    WS_I(OFF_COFS)[base+k] = run;
    run += c;
  }
  if (tid == 255) cnt[NCELL] = run;
}

// scatter candidates into cell-sorted float4 array (x, y, |c|^2, idx)
__global__ __launch_bounds__(256) void k_scatter(char* __restrict__ ws) {
  int j = blockIdx.x * 256 + threadIdx.x;
  if (j >= NCND) return;
  const unsigned* mnmx = WS_U(OFF_MNMX);
  float xmin = decf(mnmx[0]), xmax = decf(mnmx[1]);
  float ymin = decf(mnmx[2]), ymax = decf(mnmx[3]);
  float ivx = (float)GRID / ((xmax - xmin) * 1.000001f + 1e-30f);
  float ivy = (float)GRID / ((ymax - ymin) * 1.000001f + 1e-30f);
  float c0 = WS_F(OFF_CPOS)[2*j], c1 = WS_F(OFF_CPOS)[2*j+1];
  int cx = min(GRID-1, max(0, (int)((c0 - xmin) * ivx)));
  int cy = min(GRID-1, max(0, (int)((c1 - ymin) * ivy)));
  int pos = atomicAdd(&WS_I(OFF_COFS)[cy*GRID + cx], 1);
  ((float4*)(ws + OFF_SCND))[pos] =
      make_float4(c0, c1, WS_F(OFF_CSQ)[j], __int_as_float(j));
}

// ---------------- per-loop kernels ----------------

// non-destructive wave top-10 pop-merge: refreshes cur10d, lane r stores r-th idx
#define MERGEPOP() do {                                                    \
    float cd[10]; int ci[10];                                              \
    _Pragma("unroll")                                                      \
    for (int k = 0; k < 10; k++) { cd[k] = bd[k]; ci[k] = bi[k]; }         \
    _Pragma("unroll")                                                      \
    for (int r = 0; r < 10; r++) {                                         \
      float md = cd[0]; int mi = ci[0];                                    \
      _Pragma("unroll")                                                    \
      for (int off = 32; off >= 1; off >>= 1) {                            \
        float od = __shfl_xor(md, off);                                    \
        int   oi = __shfl_xor(mi, off);                                    \
        if (lexless(od, oi, md, mi)) { md = od; mi = oi; }                 \
      }                                                                    \
      bool win = (cd[0] == md) && (ci[0] == mi);                           \
      if (win) {                                                           \
        _Pragma("unroll")                                                  \
        for (int k = 0; k < 9; k++) { cd[k] = cd[k+1]; ci[k] = ci[k+1]; }  \
        cd[9] = 3.4e38f; ci[9] = 0x7FFFFFFF;                               \
      }                                                                    \
      if (lane == r) selIdx = mi;                                          \
      cur10d = md;                                                         \
    }                                                                      \
  } while (0)

// scan box rows [yA..yB] x cells [xA..xB]: each row is a CONTIGUOUS scnd span
#define SCAN_BOX(xA, xB, yA, yB) do {                                      \
    for (int _y = (yA); _y <= (yB); _y++) {                                \
      int _s = cst[_y*GRID + (xA)], _e = cst[_y*GRID + (xB) + 1];          \
      for (int _t = _s + lane; _t < _e; _t += 64) {                        \
        float4 _q = scnd[_t];                                              \
        float _d2 = (psq + _q.z) - 2.f * fmaf(p1, _q.y, p0 * _q.x);        \
        int _j = __float_as_int(_q.w);                                     \
        INSERT10(_d2, _j);                                                 \
      }                                                                    \
    }                                                                      \
  } while (0)

// blocks 0..127: one wave per path node — seed-box + exact-radius grid kNN +
//                CSR dedup + KSRC/KKEEP.
// blocks 128..191: thread-per-(node,f) u/v prep — per-block redundant BN stats
//                (path rows; cand part precomputed) so no cross-block dep.
//                Also zeroes SBUF; block 128 publishes MEAN/RSTD for loopB/C.
__global__ __launch_bounds__(256) void k_A(char* __restrict__ ws,
    const float* __restrict__ ncw1, const float* __restrict__ gamma,
    const float* __restrict__ beta) {
  __shared__ float psum[256], psq[256], xns[256], mr[64];
  int tid = threadIdx.x, b = blockIdx.x;
  float* pathb = WS_F(OFF_PATH);

  if (b < PN/4) {
    int lane = tid & 63, wave = tid >> 6;
    int node = (b << 2) + wave;
    const float4* scnd = (const float4*)(ws + OFF_SCND);
    const int* cst = WS_I(OFF_CSTART);
    const unsigned* mnmx = WS_U(OFF_MNMX);
    float xmin = decf(mnmx[0]), xmax = decf(mnmx[1]);
    float ymin = decf(mnmx[2]), ymax = decf(mnmx[3]);
    float spx = (xmax - xmin) * 1.000001f + 1e-30f;
    float spy = (ymax - ymin) * 1.000001f + 1e-30f;
    float ivx = (float)GRID / spx, ivy = (float)GRID / spy;
    float p0 = pathb[2*node], p1 = pathb[2*node+1];
    float psq_ = p0*p0 + p1*p1;
    float psq = psq_;
    int cx = min(GRID-1, max(0, (int)((p0 - xmin) * ivx)));
    int cy = min(GRID-1, max(0, (int)((p1 - ymin) * ivy)));

    // ---- phase A: grow square box (prefix-count only) until >= 10 pts ----
    int R = 1, xL, xR, yL, yR;
    for (;;) {
      xL = max(cx - R, 0); xR = min(cx + R, GRID-1);
      yL = max(cy - R, 0); yR = min(cy + R, GRID-1);
      int cnt = 0;
      for (int y = yL + lane; y <= yR; y += 64)
        cnt += cst[y*GRID + xR + 1] - cst[y*GRID + xL];
      #pragma unroll
      for (int off = 32; off >= 1; off >>= 1) cnt += __shfl_xor(cnt, off);
      if (cnt >= KK || R >= GRID) break;
      R <<= 1;
    }

    float bd[10]; int bi[10];
    #pragma unroll
    for (int k = 0; k < 10; k++) { bd[k] = 3.4e38f; bi[k] = 0x7FFFFFFF; }
    float cur10d = 3.4e38f;
    int selIdx = 0x7FFFFFFF;

    // ---- phase B: scan seed box -> d2_10 upper bound (exact within box) ----
    SCAN_BOX(xL, xR, yL, yR);
    MERGEPOP();

    // ---- phase C: exact pass over cells overlapping [p +- r] square ----
    float r = sqrtf(cur10d) * 1.000002f;
    int xL2 = min(GRID-1, max(0, (int)((p0 - r - xmin) * ivx)));
    int xR2 = min(GRID-1, max(0, (int)((p0 + r - xmin) * ivx)));
    int yL2 = min(GRID-1, max(0, (int)((p1 - r - ymin) * ivy)));
    int yR2 = min(GRID-1, max(0, (int)((p1 + r - ymin) * ivy)));
    #pragma unroll
    for (int k = 0; k < 10; k++) { bd[k] = 3.4e38f; bi[k] = 0x7FFFFFFF; }
    SCAN_BOX(xL2, xR2, yL2, yR2);
    MERGEPOP();

    // lanes 0..9 hold the rank-r neighbor; dedup vs fixed edges via tiny CSR
    if (lane < KK) {
      int srcg = selIdx + PN;
      int s = WS_I(OFF_E0START)[node], e = WS_I(OFF_E0START)[node+1];
      int keep = 1;
      for (int t = s; t < e; t++)
        if (WS_I(OFF_E0CSRS)[t] == srcg) { keep = 0; break; }
      WS_I(OFF_KSRC)[node*KK+lane]  = srcg;
      WS_I(OFF_KKEEP)[node*KK+lane] = keep;
    }
  } else {
    // ---- u/v prep, thread = (node, feature) ----
    int bu0 = b - PN/4;               // 0..63
    int f = tid & 31, rgrp = tid >> 5; // rgrp: row-group / local node
    const float* cpath = WS_F(OFF_CPATH);
    float w0 = ncw1[f], w1 = ncw1[32+f], cp = cpath[f];

    // per-block redundant BN stats over the 512 path rows (cand part is
    // precomputed in SUMC/SUMC2) — 64 rows per thread
    float s = 0.f, s2 = 0.f;
    for (int j = 0; j < 64; j++) {
      int rr = rgrp*64 + j;
      float q0 = pathb[2*rr], q1 = pathb[2*rr+1];
      float h = fmaf(q1, w1, fmaf(q0, w0, cp));
      s += h; s2 += h*h;
    }
    psum[tid] = s; psq[tid] = s2;
    __syncthreads();
    if (tid < 32) {
      float ss = 0.f, ss2 = 0.f;
      #pragma unroll
      for (int g = 0; g < 8; g++) { ss += psum[g*32+tid]; ss2 += psq[g*32+tid]; }
      float mean = (WS_F(OFF_SUMC)[tid]  + ss)  * (1.f / NNODE);
      float ex2  = (WS_F(OFF_SUMC2)[tid] + ss2) * (1.f / NNODE);
      float var  = ex2 - mean * mean;
      float rs   = 1.0f / sqrtf(var + EPSV);
      mr[tid] = mean; mr[32+tid] = rs;
      if (bu0 == 0) { WS_F(OFF_MEAN)[tid] = mean; WS_F(OFF_RSTD)[tid] = rs; }
    }
    __syncthreads();
    // xn for this block's 8 nodes
    int i = bu0*8 + rgrp;
    float p0 = pathb[2*i], p1 = pathb[2*i+1];
    float h = fmaf(p1, w1, fmaf(p0, w0, cp));
    float t = (h - mr[f]) * mr[32+f];
    t = fmaf(t, gamma[f], beta[f]);
    xns[tid] = t > 0.f ? t : 0.f;
    __syncthreads();
    const float* wcu = WS_F(OFF_WCU); const float* wcv = WS_F(OFF_WCV);
    float au = WS_F(OFF_BU)[f], av = WS_F(OFF_BV)[f];
    #pragma unroll
    for (int k = 0; k < 32; k++) {
      float x = xns[rgrp*32 + k];           // LDS broadcast within 32 lanes
      au = fmaf(x, wcu[k*32+f], au);        // coalesced 128B line per k
      av = fmaf(x, wcv[k*32+f], av);
    }
    WS_F(OFF_UPATH)[i*32+f] = au;           // fully coalesced stores
    WS_F(OFF_VDST)[i*32+f]  = av;
    WS_F(OFF_SBUF)[i*32+f]  = 0.f;
  }
}

// per-edge: r = relu(u[src]+v[dst]) accumulated into S[dst]
__global__ __launch_bounds__(256) void k_loopB(char* __restrict__ ws,
    const float* __restrict__ ncw1, const float* __restrict__ gamma,
    const float* __restrict__ beta) {
  int t = blockIdx.x * 256 + threadIdx.x;
  int src, dst;
  if (t < PN*KK) {
    dst = t / KK;
    src = WS_I(OFF_KSRC)[t];
    if (!WS_I(OFF_KKEEP)[t]) return;
  } else {
    int e = t - PN*KK;
    if (e >= *WS_I(OFF_E0C)) return;
    src = WS_I(OFF_E0S)[e];
    dst = WS_I(OFF_E0D)[e];
  }
  float u[32];
  if (src < PN) {
    const float4* up4 = (const float4*)&WS_F(OFF_UPATH)[src*32];
    #pragma unroll
    for (int q = 0; q < 8; q++) {
      float4 w = up4[q];
      u[4*q] = w.x; u[4*q+1] = w.y; u[4*q+2] = w.z; u[4*q+3] = w.w;
    }
  } else {
    int j = src - PN;
    float c0 = WS_F(OFF_CPOS)[2*j], c1 = WS_F(OFF_CPOS)[2*j+1];
    const float* cls = (j < NFREE) ? WS_F(OFF_CFREE) : WS_F(OFF_CCOL);
    const float* mean = WS_F(OFF_MEAN); const float* rstd = WS_F(OFF_RSTD);
    float xn[32];
    #pragma unroll
    for (int f = 0; f < 32; f++) {
      float h = fmaf(c1, ncw1[32+f], fmaf(c0, ncw1[f], cls[f]));
      float tt = (h - mean[f]) * rstd[f];
      tt = fmaf(tt, gamma[f], beta[f]);
      xn[f] = tt > 0.f ? tt : 0.f;
    }
    const float* wcu = WS_F(OFF_WCU); const float* bu = WS_F(OFF_BU);
    for (int f = 0; f < 32; f++) {
      float au = bu[f];
      #pragma unroll
      for (int k = 0; k < 32; k++) au = fmaf(xn[k], wcu[k*32+f], au);
      u[f] = au;
    }
  }
  const float* vd = &WS_F(OFF_VDST)[dst*32];
  float* sb = &WS_F(OFF_SBUF)[dst*32];
  #pragma unroll
  for (int f = 0; f < 32; f++) {
    float r = u[f] + vd[f];
    if (r > 0.f) atomicAdd(&sb[f], r);
  }
}

// epilogue per path node: out -> mp1 -> h = x + g -> smooth -> path update + d_out
__global__ __launch_bounds__(256) void k_loopC(char* __restrict__ ws,
    const float* __restrict__ ncw1, const float* __restrict__ gamma,
    const float* __restrict__ beta, const float* __restrict__ ncw2,
    const float* __restrict__ ncb2, const float* __restrict__ m0w2,
    const float* __restrict__ m0b2, const float* __restrict__ m1w1,
    const float* __restrict__ m1b1, const float* __restrict__ m1w2,
    const float* __restrict__ m1b2, const float* __restrict__ snw,
    const float* __restrict__ snb, float* __restrict__ outp) {
  int i = blockIdx.x * 256 + threadIdx.x;
  if (i >= PN) return;
  float s[32];
  #pragma unroll
  for (int f = 0; f < 32; f++) s[f] = WS_F(OFF_SBUF)[i*32+f];
  int deg = WS_I(OFF_DEG0)[i];
  #pragma unroll
  for (int k = 0; k < KK; k++) deg += WS_I(OFF_KKEEP)[i*KK+k];
  float fdeg = (float)deg;

  float o[32];
  for (int f = 0; f < 32; f++) {
    float acc = 0.f;
    #pragma unroll
    for (int k = 0; k < 32; k++) acc = fmaf(s[k], m0w2[k*32+f], acc);
    o[f] = fmaf(fdeg, m0b2[f], acc);
  }
  float t[32];
  for (int f = 0; f < 32; f++) {
    float acc = m1b1[f];
    #pragma unroll
    for (int k = 0; k < 32; k++) acc = fmaf(o[k], m1w1[k*32+f], acc);
    t[f] = acc > 0.f ? acc : 0.f;
  }
  float g[32];
  for (int f = 0; f < 32; f++) {
    float acc = m1b2[f];
    #pragma unroll
    for (int k = 0; k < 32; k++) acc = fmaf(t[k], m1w2[k*32+f], acc);
    g[f] = acc;
  }
  float p0 = WS_F(OFF_PATH)[2*i], p1 = WS_F(OFF_PATH)[2*i+1];
  const float* cpath = WS_F(OFF_CPATH);
  const float* mean = WS_F(OFF_MEAN); const float* rstd = WS_F(OFF_RSTD);
  float xn[32];
  #pragma unroll
  for (int f = 0; f < 32; f++) {
    float h = fmaf(p1, ncw1[32+f], fmaf(p0, ncw1[f], cpath[f]));
    float tt = (h - mean[f]) * rstd[f];
    tt = fmaf(tt, gamma[f], beta[f]);
    xn[f] = tt > 0.f ? tt : 0.f;
  }
  float sm0 = snb[0], sm1 = snb[1];
  for (int f = 0; f < 32; f++) {
    float acc = ncb2[f];
    #pragma unroll
    for (int k = 0; k < 32; k++) acc = fmaf(xn[k], ncw2[k*32+f], acc);
    float h = acc + g[f];
    sm0 = fmaf(h, snw[2*f],   sm0);
    sm1 = fmaf(h, snw[2*f+1], sm1);
  }
  float np0, np1;
  if (i == 0 || i == PN-1) { np0 = p0; np1 = p1; }
  else                     { np0 = sm0; np1 = sm1; }
  WS_F(OFF_PATH)[2*i]   = np0;
  WS_F(OFF_PATH)[2*i+1] = np1;
  outp[2*i]   = np0;
  outp[2*i+1] = np1;
}

// ---------------- host launch ----------------

extern "C" void kernel_launch(void* const* d_in, const int* in_sizes, int n_in,
                              void* d_out, int out_size, void* d_ws, size_t ws_size,
                              hipStream_t stream) {
  const float* path  = (const float*)d_in[0];
  const float* freep = (const float*)d_in[1];
  const float* collp = (const float*)d_in[2];
  const int*   ei    = (const int*)d_in[4];
  const float* ncw1  = (const float*)d_in[6];
  const float* ncb1  = (const float*)d_in[7];
  const float* gamma = (const float*)d_in[8];
  const float* beta  = (const float*)d_in[9];
  const float* ncw2  = (const float*)d_in[10];
  const float* ncb2  = (const float*)d_in[11];
  const float* m0w1  = (const float*)d_in[12];
  const float* m0b1  = (const float*)d_in[13];
  const float* m0w2  = (const float*)d_in[14];
  const float* m0b2  = (const float*)d_in[15];
  const float* m1w1  = (const float*)d_in[16];
  const float* m1b1  = (const float*)d_in[17];
  const float* m1w2  = (const float*)d_in[18];
  const float* m1b2  = (const float*)d_in[19];
  const float* snw   = (const float*)d_in[20];
  const float* snb   = (const float*)d_in[21];
  char* ws = (char*)d_ws;

  k_init   <<<HSIZE/256, 256, 0, stream>>>(ws, path);
  k_cand   <<<(NCND+255)/256, 256, 0, stream>>>(ws, freep, collp, ncw1, ncb1);
  k_wprep  <<<1, 1024, 0, stream>>>(ws, m0w1, m0b1, ncw1, ncb1, ncw2, ncb2);
  k_edges  <<<(NEDGE+255)/256, 256, 0, stream>>>(ws, ei);
  k_csr    <<<1, 256, 0, stream>>>(ws);
  k_hist   <<<(NCND+255)/256, 256, 0, stream>>>(ws);
  k_scan   <<<1, 256, 0, stream>>>(ws);
  k_scatter<<<(NCND+255)/256, 256, 0, stream>>>(ws);

  for (int l = 0; l < NLOOP; l++) {
    k_A    <<<PN/4 + PN/8, 256, 0, stream>>>(ws, ncw1, gamma, beta);
    k_loopB<<<(PN*KK + E0CAP + 255)/256, 256, 0, stream>>>(ws, ncw1, gamma, beta);
    k_loopC<<<2, 256, 0, stream>>>(ws, ncw1, gamma, beta, ncw2, ncb2,
                                   m0w2, m0b2, m1w1, m1b1, m1w2, m1b2,
                                   snw, snb, (float*)d_out);
  }
}

// Round 7
// 377.166 us; speedup vs baseline: 4.6134x; 1.7261x over previous
//
#include <hip/hip_runtime.h>
#include <stdint.h>

// Problem constants (fixed by setup_inputs)
#define PN     512
#define NFREE  50000
#define NCND   100000
#define NNODE  100512
#define NEDGE  300000
#define KK     10
#define NLOOP  5
#define EPSV   1e-5f

#define GRID   128
#define NCELL  (GRID*GRID)

#define HSIZE  8192          // small: only dst<PN edges (~1530) get hashed
#define HMASK  (HSIZE-1)
#define E0CAP  4096
#define EMPTYK 0xFFFFFFFFFFFFFFFFull

#define NCB    ((NCND+255)/256)    // 391 candidate blocks
#define NEB    ((NEDGE+255)/256)   // 1172 edge blocks

// workspace layout (bytes) — ~3.9 MB
#define OFF_HASH    ((size_t)0)
#define OFF_CPOS    (OFF_HASH    + (size_t)HSIZE*8)      // 65536
#define OFF_CSQ     (OFF_CPOS    + 800000)
#define OFF_SCND    (OFF_CSQ     + 400000)               // float4/cand, cell-sorted
#define OFF_CSTART  (OFF_SCND    + 1600000)              // NCELL+1 ints
#define OFF_COFS    (OFF_CSTART  + 65600)
#define OFF_MNMX    (OFF_COFS    + 65600)                // 4 encoded uints
#define OFF_MOM     (OFF_MNMX    + 64)                   // 10 floats: F{s0,s1,s00,s11,s01} C{...}
#define OFF_MEAN    (OFF_MOM     + 64)
#define OFF_RSTD    (OFF_MEAN    + 128)
#define OFF_WCU     (OFF_RSTD    + 128)
#define OFF_WCV     (OFF_WCU     + 4096)
#define OFF_BU      (OFF_WCV     + 4096)
#define OFF_BV      (OFF_BU      + 128)
#define OFF_CPATH   (OFF_BV      + 128)
#define OFF_CFREE   (OFF_CPATH   + 128)
#define OFF_CCOL    (OFF_CFREE   + 128)
#define OFF_PATH    (OFF_CCOL    + 128)                  // 16-aligned
#define OFF_UPATH   (OFF_PATH    + 4096)
#define OFF_VDST    (OFF_UPATH   + 65536)
#define OFF_UKNN    (OFF_VDST    + 65536)                // PN*KK*32 floats
#define OFF_E0S     (OFF_UKNN    + 655360)
#define OFF_E0D     (OFF_E0S     + (size_t)E0CAP*4)
#define OFF_DEG0    (OFF_E0D     + (size_t)E0CAP*4)
#define OFF_E0C     (OFF_DEG0    + 2048)
#define OFF_KSRC    (OFF_E0C     + 64)
#define OFF_KKEEP   (OFF_KSRC    + (size_t)PN*KK*4)
#define OFF_E0START (OFF_KKEEP   + (size_t)PN*KK*4)      // 513 ints (pad 2112)
#define OFF_E0OFS   (OFF_E0START + 2112)
#define OFF_E0CSRS  (OFF_E0OFS   + 2048)                 // E0CAP ints

#define WS_F(o)  ((float*)(ws + (o)))
#define WS_I(o)  ((int*)(ws + (o)))
#define WS_U(o)  ((unsigned*)(ws + (o)))
#define WS_H(o)  ((unsigned long long*)(ws + (o)))

__device__ __forceinline__ bool lexless(float da, int ia, float db, int ib) {
  return (da < db) || (da == db && ia < ib);
}

__device__ __forceinline__ uint32_t hslot(unsigned long long key) {
  return (uint32_t)((key * 0x9E3779B97F4A7C15ull) >> 40) & HMASK;
}

// monotone float<->uint order encoding (for atomicMin/Max on floats)
__device__ __forceinline__ unsigned encf(float f) {
  unsigned u = __float_as_uint(f);
  return (u & 0x80000000u) ? ~u : (u | 0x80000000u);
}
__device__ __forceinline__ float decf(unsigned u) {
  return (u & 0x80000000u) ? __uint_as_float(u & 0x7FFFFFFFu) : __uint_as_float(~u);
}

// BN mean/rstd from analytic moments: cand moments (global MOM, per class) +
// path moments (pm*) supplied by caller.  Sums are linear/quadratic in coords.
__device__ __forceinline__ void bn_from_moments(const char* ws,
    float w0, float w1, float cp, float clsF, float clsC,
    float pm0, float pm1, float pm00, float pm11, float pm01,
    float* meano, float* rstdo) {
  const float* M = (const float*)(ws + OFF_MOM);
  float sF0=M[0], sF1=M[1], sF00=M[2], sF11=M[3], sF01=M[4];
  float sC0=M[5], sC1=M[6], sC00=M[7], sC11=M[8], sC01=M[9];
  const float NC = (float)(NCND - NFREE);
  float sh  = w0*(sF0+sC0+pm0) + w1*(sF1+sC1+pm1)
            + (float)NFREE*clsF + NC*clsC + (float)PN*cp;
  float sh2 = w0*w0*(sF00+sC00+pm00) + w1*w1*(sF11+sC11+pm11)
            + 2.f*w0*w1*(sF01+sC01+pm01)
            + 2.f*w0*(clsF*sF0 + clsC*sC0 + cp*pm0)
            + 2.f*w1*(clsF*sF1 + clsC*sC1 + cp*pm1)
            + (float)NFREE*clsF*clsF + NC*clsC*clsC + (float)PN*cp*cp;
  float mean = sh  * (1.f / NNODE);
  float ex2  = sh2 * (1.f / NNODE);
  float var  = ex2 - mean * mean;
  *meano = mean;
  *rstdo = 1.0f / sqrtf(var + EPSV);
}

#define INSERT10(d2v, jv)                                                  \
  if (lexless((d2v), (jv), bd[9], bi[9])) {                                \
    bool placed = false;                                                   \
    _Pragma("unroll")                                                      \
    for (int k = 9; k > 0; k--) {                                          \
      bool shift = !placed && lexless((d2v), (jv), bd[k-1], bi[k-1]);      \
      bool here  = !placed && !shift;                                      \
      if (here)       { bd[k] = (d2v); bi[k] = (jv); placed = true; }      \
      else if (shift) { bd[k] = bd[k-1]; bi[k] = bi[k-1]; }                \
    }                                                                      \
    if (!placed) { bd[0] = (d2v); bi[0] = (jv); }                          \
  }

// ---------------- setup kernels ----------------

__global__ __launch_bounds__(256) void k_init0(char* __restrict__ ws,
                                               const float* __restrict__ path_in) {
  unsigned i = blockIdx.x * 256u + threadIdx.x;       // grid = 64 → 16384 threads
  if (i < HSIZE) WS_H(OFF_HASH)[i] = EMPTYK;
  if (i < NCELL) WS_I(OFF_CSTART)[i] = 0;
  if (i < 1024)  WS_F(OFF_PATH)[i] = path_in[i];
  if (i < 512)   WS_I(OFF_DEG0)[i] = 0;
  if (i < 16)    WS_F(OFF_MOM)[i] = 0.f;
  if (i < 4)     WS_U(OFF_MNMX)[i] = (i & 1) ? 0u : 0xFFFFFFFFu;
  if (i == 0) { *WS_I(OFF_E0C) = 0; WS_I(OFF_CSTART)[NCELL] = 0; }
}

// roles: b<NCB cand (pos/norm/bbox/moments) | b<NCB+NEB edge filter+dedup | last: wprep
__global__ __launch_bounds__(256) void k_setupA(char* __restrict__ ws,
    const float* __restrict__ freep, const float* __restrict__ collp,
    const int* __restrict__ ei,
    const float* __restrict__ ncw1, const float* __restrict__ ncb1,
    const float* __restrict__ m0w1, const float* __restrict__ m0b1,
    const float* __restrict__ ncw2, const float* __restrict__ ncb2) {
  int b = blockIdx.x, tid = threadIdx.x;
  if (b < NCB) {
    __shared__ float pm[4][10];
    __shared__ unsigned bb[4][4];
    int j = b*256 + tid;
    bool valid = (j < NCND);
    float c0 = 0.f, c1 = 0.f;
    if (valid) {
      if (j < NFREE) { c0 = freep[2*j];          c1 = freep[2*j+1]; }
      else           { c0 = collp[2*(j-NFREE)];  c1 = collp[2*(j-NFREE)+1]; }
      ((float2*)(ws + OFF_CPOS))[j] = make_float2(c0, c1);
      WS_F(OFF_CSQ)[j] = c0*c0 + c1*c1;
    }
    bool isF = valid && (j < NFREE), isC = valid && (j >= NFREE);
    float v[10];
    v[0]=isF?c0:0.f; v[1]=isF?c1:0.f; v[2]=isF?c0*c0:0.f; v[3]=isF?c1*c1:0.f; v[4]=isF?c0*c1:0.f;
    v[5]=isC?c0:0.f; v[6]=isC?c1:0.f; v[7]=isC?c0*c0:0.f; v[8]=isC?c1*c1:0.f; v[9]=isC?c0*c1:0.f;
    #pragma unroll
    for (int q = 0; q < 10; q++)
      #pragma unroll
      for (int off = 32; off >= 1; off >>= 1) v[q] += __shfl_xor(v[q], off);
    unsigned e0n = valid ? encf(c0) : 0xFFFFFFFFu, e0x = valid ? encf(c0) : 0u;
    unsigned e1n = valid ? encf(c1) : 0xFFFFFFFFu, e1x = valid ? encf(c1) : 0u;
    #pragma unroll
    for (int off = 32; off >= 1; off >>= 1) {
      e0n = min(e0n, (unsigned)__shfl_xor((int)e0n, off));
      e0x = max(e0x, (unsigned)__shfl_xor((int)e0x, off));
      e1n = min(e1n, (unsigned)__shfl_xor((int)e1n, off));
      e1x = max(e1x, (unsigned)__shfl_xor((int)e1x, off));
    }
    int wv = tid >> 6, lane = tid & 63;
    if (lane == 0) {
      #pragma unroll
      for (int q = 0; q < 10; q++) pm[wv][q] = v[q];
      bb[wv][0]=e0n; bb[wv][1]=e0x; bb[wv][2]=e1n; bb[wv][3]=e1x;
    }
    __syncthreads();
    if (tid < 10)
      atomicAdd(&WS_F(OFF_MOM)[tid], pm[0][tid]+pm[1][tid]+pm[2][tid]+pm[3][tid]);
    if (tid < 4) {
      unsigned a0=bb[0][tid], a1=bb[1][tid], a2=bb[2][tid], a3=bb[3][tid];
      if (tid & 1) atomicMax(&WS_U(OFF_MNMX)[tid], max(max(a0,a1),max(a2,a3)));
      else         atomicMin(&WS_U(OFF_MNMX)[tid], min(min(a0,a1),min(a2,a3)));
    }
  } else if (b < NCB + NEB) {
    int e = (b - NCB)*256 + tid;
    if (e >= NEDGE) return;
    int src = ei[e], dst = ei[NEDGE + e];
    if (dst >= PN) return;                         // only dst<PN edges matter
    unsigned long long key = (unsigned long long)src * NNODE + (unsigned long long)dst;
    unsigned long long* hash = WS_H(OFF_HASH);
    uint32_t slot = hslot(key);
    for (;;) {
      unsigned long long prev = atomicCAS(&hash[slot], EMPTYK, key);
      if (prev == EMPTYK) {
        int pos = atomicAdd(WS_I(OFF_E0C), 1);
        if (pos < E0CAP) {
          WS_I(OFF_E0S)[pos] = src;
          WS_I(OFF_E0D)[pos] = dst;
          atomicAdd(&WS_I(OFF_DEG0)[dst], 1);
        }
        break;
      }
      if (prev == key) break;
      slot = (slot + 1) & HMASK;
    }
  } else {
    // wprep role (256 threads × 4 iters)
    __shared__ float Wu[1024], Wv[1024];
    for (int it = 0; it < 4; it++) {
      int idx = it*256 + tid, k = idx >> 5, g = idx & 31;
      float a = m0w1[k*32+g], b2 = m0w1[(k+32)*32+g], c = m0w1[(k+64)*32+g];
      Wu[idx] = a + b2;  Wv[idx] = c - a;
    }
    __syncthreads();
    for (int it = 0; it < 4; it++) {
      int idx = it*256 + tid, k = idx >> 5, g = idx & 31;
      float au = 0.f, av = 0.f;
      #pragma unroll
      for (int f = 0; f < 32; f++) {
        float w2 = ncw2[k*32+f];
        au = fmaf(w2, Wu[f*32+g], au);
        av = fmaf(w2, Wv[f*32+g], av);
      }
      WS_F(OFF_WCU)[idx] = au;  WS_F(OFF_WCV)[idx] = av;
    }
    if (tid < 32) {
      float bu = 0.f, bv = 0.f;
      #pragma unroll
      for (int f = 0; f < 32; f++) {
        bu = fmaf(ncb2[f], Wu[f*32+tid], bu);
        bv = fmaf(ncb2[f], Wv[f*32+tid], bv);
      }
      WS_F(OFF_BU)[tid] = bu;
      WS_F(OFF_BV)[tid] = bv + m0b1[tid];
      WS_F(OFF_CPATH)[tid] = ncw1[64+tid]  + ncb1[tid];
      WS_F(OFF_CFREE)[tid] = ncw1[96+tid]  + ncb1[tid];
      WS_F(OFF_CCOL)[tid]  = ncw1[128+tid] + ncb1[tid];
    }
  }
}

// roles: b<NCB hist | b==NCB csr build
__global__ __launch_bounds__(256) void k_setupB(char* __restrict__ ws) {
  int b = blockIdx.x, tid = threadIdx.x;
  if (b < NCB) {
    int j = b*256 + tid;
    if (j >= NCND) return;
    const unsigned* mnmx = WS_U(OFF_MNMX);
    float xmin = decf(mnmx[0]), xmax = decf(mnmx[1]);
    float ymin = decf(mnmx[2]), ymax = decf(mnmx[3]);
    float ivx = (float)GRID / ((xmax - xmin) * 1.000001f + 1e-30f);
    float ivy = (float)GRID / ((ymax - ymin) * 1.000001f + 1e-30f);
    float2 c = ((const float2*)(ws + OFF_CPOS))[j];
    int cx = min(GRID-1, max(0, (int)((c.x - xmin) * ivx)));
    int cy = min(GRID-1, max(0, (int)((c.y - ymin) * ivy)));
    atomicAdd(&WS_I(OFF_CSTART)[cy*GRID + cx], 1);
  } else {
    __shared__ int sc[512];
    sc[tid]     = WS_I(OFF_DEG0)[tid];
    sc[256+tid] = WS_I(OFF_DEG0)[256+tid];
    __syncthreads();
    if (tid == 0) {
      int run = 0;
      for (int i = 0; i < 512; i++) { int c = sc[i]; sc[i] = run; run += c; }
      WS_I(OFF_E0START)[512] = run;
    }
    __syncthreads();
    WS_I(OFF_E0START)[tid]     = sc[tid];
    WS_I(OFF_E0START)[256+tid] = sc[256+tid];
    WS_I(OFF_E0OFS)[tid]       = sc[tid];
    WS_I(OFF_E0OFS)[256+tid]   = sc[256+tid];
    __syncthreads();
    int n = *WS_I(OFF_E0C); if (n > E0CAP) n = E0CAP;
    for (int e = tid; e < n; e += 256) {
      int dst = WS_I(OFF_E0D)[e];
      int pos = atomicAdd(&WS_I(OFF_E0OFS)[dst], 1);
      WS_I(OFF_E0CSRS)[pos] = WS_I(OFF_E0S)[e];
    }
  }
}

__global__ __launch_bounds__(256) void k_scan(char* __restrict__ ws) {
  __shared__ int part[256];
  int tid = threadIdx.x;
  int* cnt = WS_I(OFF_CSTART);
  int base = tid * (NCELL/256);
  int sum = 0;
  for (int k = 0; k < NCELL/256; k++) sum += cnt[base+k];
  part[tid] = sum;
  __syncthreads();
  for (int off = 1; off < 256; off <<= 1) {
    int t = (tid >= off) ? part[tid - off] : 0;
    __syncthreads();
    part[tid] += t;
    __syncthreads();
  }
  int run = part[tid] - sum;
  for (int k = 0; k < NCELL/256; k++) {
    int c = cnt[base+k];
    cnt[base+k] = run;
    WS_I(OFF_COFS)[base+k] = run;
    run += c;
  }
  if (tid == 255) cnt[NCELL] = run;
}

__global__ __launch_bounds__(256) void k_scatter(char* __restrict__ ws) {
  int j = blockIdx.x * 256 + threadIdx.x;
  if (j >= NCND) return;
  const unsigned* mnmx = WS_U(OFF_MNMX);
  float xmin = decf(mnmx[0]), xmax = decf(mnmx[1]);
  float ymin = decf(mnmx[2]), ymax = decf(mnmx[3]);
  float ivx = (float)GRID / ((xmax - xmin) * 1.000001f + 1e-30f);
  float ivy = (float)GRID / ((ymax - ymin) * 1.000001f + 1e-30f);
  float2 c = ((const float2*)(ws + OFF_CPOS))[j];
  int cx = min(GRID-1, max(0, (int)((c.x - xmin) * ivx)));
  int cy = min(GRID-1, max(0, (int)((c.y - ymin) * ivy)));
  int pos = atomicAdd(&WS_I(OFF_COFS)[cy*GRID + cx], 1);
  ((float4*)(ws + OFF_SCND))[pos] =
      make_float4(c.x, c.y, WS_F(OFF_CSQ)[j], __int_as_float(j));
}

// ---------------- per-loop kernels ----------------

#define MERGEPOP() do {                                                    \
    float cd[10]; int ci[10];                                              \
    _Pragma("unroll")                                                      \
    for (int k = 0; k < 10; k++) { cd[k] = bd[k]; ci[k] = bi[k]; }         \
    _Pragma("unroll")                                                      \
    for (int r = 0; r < 10; r++) {                                         \
      float md = cd[0]; int mi = ci[0];                                    \
      _Pragma("unroll")                                                    \
      for (int off = 32; off >= 1; off >>= 1) {                            \
        float od = __shfl_xor(md, off);                                    \
        int   oi = __shfl_xor(mi, off);                                    \
        if (lexless(od, oi, md, mi)) { md = od; mi = oi; }                 \
      }                                                                    \
      bool win = (cd[0] == md) && (ci[0] == mi);                           \
      if (win) {                                                           \
        _Pragma("unroll")                                                  \
        for (int k = 0; k < 9; k++) { cd[k] = cd[k+1]; ci[k] = ci[k+1]; }  \
        cd[9] = 3.4e38f; ci[9] = 0x7FFFFFFF;                               \
      }                                                                    \
      if (lane == r) selIdx = mi;                                          \
      cur10d = md;                                                         \
    }                                                                      \
  } while (0)

#define SCAN_BOX(xA, xB, yA, yB) do {                                      \
    for (int _y = (yA); _y <= (yB); _y++) {                                \
      int _s = cst[_y*GRID + (xA)], _e = cst[_y*GRID + (xB) + 1];          \
      for (int _t = _s + lane; _t < _e; _t += 64) {                        \
        float4 _q = scnd[_t];                                              \
        float _d2 = (psq + _q.z) - 2.f * fmaf(p1, _q.y, p0 * _q.x);        \
        int _j = __float_as_int(_q.w);                                     \
        INSERT10(_d2, _j);                                                 \
      }                                                                    \
    }                                                                      \
  } while (0)

// blocks 0..127: wave-per-node kNN + CSR dedup + BN(analytic) + u for own 10 srcs
// blocks 128..191: thread-per-(node,f) u/v prep (BN analytic, no cross-block dep)
__global__ __launch_bounds__(256) void k_A(char* __restrict__ ws,
    const float* __restrict__ ncw1, const float* __restrict__ gamma,
    const float* __restrict__ beta) {
  __shared__ float wm[4][5], momS[5], xns[256];
  int tid = threadIdx.x, b = blockIdx.x;
  float* pathb = WS_F(OFF_PATH);

  if (b < PN/4) {
    int lane = tid & 63;
    int node = (b << 2) + (tid >> 6);
    const float4* scnd = (const float4*)(ws + OFF_SCND);
    const int* cst = WS_I(OFF_CSTART);
    const unsigned* mnmx = WS_U(OFF_MNMX);
    float xmin = decf(mnmx[0]), xmax = decf(mnmx[1]);
    float ymin = decf(mnmx[2]), ymax = decf(mnmx[3]);
    float spx = (xmax - xmin) * 1.000001f + 1e-30f;
    float spy = (ymax - ymin) * 1.000001f + 1e-30f;
    float ivx = (float)GRID / spx, ivy = (float)GRID / spy;
    float p0 = pathb[2*node], p1 = pathb[2*node+1];
    float psq = p0*p0 + p1*p1;
    int cx = min(GRID-1, max(0, (int)((p0 - xmin) * ivx)));
    int cy = min(GRID-1, max(0, (int)((p1 - ymin) * ivy)));

    // phase A: grow square box until >=10 pts (prefix counts only)
    int R = 1, xL, xR, yL, yR;
    for (;;) {
      xL = max(cx - R, 0); xR = min(cx + R, GRID-1);
      yL = max(cy - R, 0); yR = min(cy + R, GRID-1);
      int cnt = 0;
      for (int y = yL + lane; y <= yR; y += 64)
        cnt += cst[y*GRID + xR + 1] - cst[y*GRID + xL];
      #pragma unroll
      for (int off = 32; off >= 1; off >>= 1) cnt += __shfl_xor(cnt, off);
      if (cnt >= KK || R >= GRID) break;
      R <<= 1;
    }

    float bd[10]; int bi[10];
    #pragma unroll
    for (int k = 0; k < 10; k++) { bd[k] = 3.4e38f; bi[k] = 0x7FFFFFFF; }
    float cur10d = 3.4e38f;
    int selIdx = 0x7FFFFFFF;

    // phase B: seed box scan (coalesced row spans)
    SCAN_BOX(xL, xR, yL, yR);
    MERGEPOP();

    // phase C: exact re-scan of cells overlapping [p +- r]
    float r = sqrtf(cur10d) * 1.000002f;
    int xL2 = min(GRID-1, max(0, (int)((p0 - r - xmin) * ivx)));
    int xR2 = min(GRID-1, max(0, (int)((p0 + r - xmin) * ivx)));
    int yL2 = min(GRID-1, max(0, (int)((p1 - r - ymin) * ivy)));
    int yR2 = min(GRID-1, max(0, (int)((p1 + r - ymin) * ivy)));
    #pragma unroll
    for (int k = 0; k < 10; k++) { bd[k] = 3.4e38f; bi[k] = 0x7FFFFFFF; }
    SCAN_BOX(xL2, xR2, yL2, yR2);
    MERGEPOP();

    // dedup vs fixed edges (tiny CSR); write KSRC/KKEEP
    if (lane < KK) {
      int srcg = selIdx + PN;
      int s = WS_I(OFF_E0START)[node], e = WS_I(OFF_E0START)[node+1];
      int keep = 1;
      for (int t = s; t < e; t++)
        if (WS_I(OFF_E0CSRS)[t] == srcg) { keep = 0; break; }
      WS_I(OFF_KSRC)[node*KK+lane]  = srcg;
      WS_I(OFF_KKEEP)[node*KK+lane] = keep;
    }

    // BN via analytic moments (path part: 8 rows/lane + butterfly)
    int fA = lane & 31;
    float w0 = ncw1[fA], w1 = ncw1[32+fA], cp = WS_F(OFF_CPATH)[fA];
    float pm0=0,pm1=0,pm00=0,pm11=0,pm01=0;
    for (int r2 = lane; r2 < PN; r2 += 64) {
      float q0 = pathb[2*r2], q1 = pathb[2*r2+1];
      pm0+=q0; pm1+=q1; pm00+=q0*q0; pm11+=q1*q1; pm01+=q0*q1;
    }
    #pragma unroll
    for (int off = 32; off >= 1; off >>= 1) {
      pm0+=__shfl_xor(pm0,off); pm1+=__shfl_xor(pm1,off); pm00+=__shfl_xor(pm00,off);
      pm11+=__shfl_xor(pm11,off); pm01+=__shfl_xor(pm01,off);
    }
    float clsF = WS_F(OFF_CFREE)[fA], clsC = WS_F(OFF_CCOL)[fA];
    float mean, rstd;
    bn_from_moments(ws, w0, w1, cp, clsF, clsC, pm0, pm1, pm00, pm11, pm01, &mean, &rstd);
    float gm = gamma[fA], bt = beta[fA], buf = WS_F(OFF_BU)[fA];
    const float* wcu = WS_F(OFF_WCU);

    // u for this node's 10 kNN srcs (all are candidates); shfl-dot over 32 feats
    for (int k = 0; k < KK; k++) {
      int jj = __shfl(selIdx, k);
      float c0 = WS_F(OFF_CPOS)[2*jj], c1 = WS_F(OFF_CPOS)[2*jj+1];
      float clsv = (jj < NFREE) ? clsF : clsC;
      float h = fmaf(c1, w1, fmaf(c0, w0, clsv));
      float xnf = fmaf((h - mean) * rstd, gm, bt);
      xnf = xnf > 0.f ? xnf : 0.f;
      float au = buf;
      #pragma unroll
      for (int m = 0; m < 32; m++)
        au = fmaf(__shfl(xnf, m), wcu[m*32+fA], au);
      if (lane < 32) WS_F(OFF_UKNN)[(node*KK+k)*32 + fA] = au;
    }
  } else {
    // u/v prep: thread = (node, f)
    int bu0 = b - PN/4;                 // 0..63
    int f = tid & 31, rgrp = tid >> 5;
    float pm0,pm1,pm00,pm11,pm01;
    {
      float4 q = ((const float4*)pathb)[tid];   // rows 2tid, 2tid+1
      pm0 = q.x+q.z; pm1 = q.y+q.w;
      pm00 = q.x*q.x+q.z*q.z; pm11 = q.y*q.y+q.w*q.w; pm01 = q.x*q.y+q.z*q.w;
    }
    #pragma unroll
    for (int off = 32; off >= 1; off >>= 1) {
      pm0+=__shfl_xor(pm0,off); pm1+=__shfl_xor(pm1,off); pm00+=__shfl_xor(pm00,off);
      pm11+=__shfl_xor(pm11,off); pm01+=__shfl_xor(pm01,off);
    }
    int wv = tid >> 6, lane = tid & 63;
    if (lane == 0) { wm[wv][0]=pm0; wm[wv][1]=pm1; wm[wv][2]=pm00; wm[wv][3]=pm11; wm[wv][4]=pm01; }
    __syncthreads();
    if (tid < 5) momS[tid] = wm[0][tid]+wm[1][tid]+wm[2][tid]+wm[3][tid];
    __syncthreads();
    float w0 = ncw1[f], w1 = ncw1[32+f], cp = WS_F(OFF_CPATH)[f];
    float clsF = WS_F(OFF_CFREE)[f], clsC = WS_F(OFF_CCOL)[f];
    float mean, rstd;
    bn_from_moments(ws, w0, w1, cp, clsF, clsC,
                    momS[0], momS[1], momS[2], momS[3], momS[4], &mean, &rstd);
    if (bu0 == 0 && rgrp == 0) { WS_F(OFF_MEAN)[f] = mean; WS_F(OFF_RSTD)[f] = rstd; }
    int i = bu0*8 + rgrp;
    float p0 = pathb[2*i], p1 = pathb[2*i+1];
    float h = fmaf(p1, w1, fmaf(p0, w0, cp));
    float t = fmaf((h - mean) * rstd, gamma[f], beta[f]);
    xns[tid] = t > 0.f ? t : 0.f;
    __syncthreads();
    const float* wcu = WS_F(OFF_WCU); const float* wcv = WS_F(OFF_WCV);
    float au = WS_F(OFF_BU)[f], av = WS_F(OFF_BV)[f];
    #pragma unroll
    for (int k = 0; k < 32; k++) {
      float x = xns[rgrp*32 + k];
      au = fmaf(x, wcu[k*32+f], au);
      av = fmaf(x, wcv[k*32+f], av);
    }
    WS_F(OFF_UPATH)[i*32+f] = au;
    WS_F(OFF_VDST)[i*32+f]  = av;
  }
}

// fused message+epilogue: thread = (dst, f); 8 dsts/block, grid 64
__global__ __launch_bounds__(256) void k_BC(char* __restrict__ ws,
    const float* __restrict__ ncw1, const float* __restrict__ gamma,
    const float* __restrict__ beta, const float* __restrict__ ncw2,
    const float* __restrict__ ncb2, const float* __restrict__ m0w2,
    const float* __restrict__ m0b2, const float* __restrict__ m1w1,
    const float* __restrict__ m1b1, const float* __restrict__ m1w2,
    const float* __restrict__ m1b2, const float* __restrict__ snw,
    const float* __restrict__ snb, float* __restrict__ outp) {
  __shared__ float A[8][33], B[8][33];
  int tid = threadIdx.x, g = tid >> 5, f = tid & 31;
  int dst = blockIdx.x*8 + g;
  float mean = WS_F(OFF_MEAN)[f], rstd = WS_F(OFF_RSTD)[f];
  float vf = WS_F(OFF_VDST)[dst*32+f];
  float S = 0.f; int deg = 0;
  #pragma unroll
  for (int k = 0; k < KK; k++) {
    int keep = WS_I(OFF_KKEEP)[dst*KK+k];
    float u = WS_F(OFF_UKNN)[(dst*KK+k)*32 + f];
    float r = u + vf;
    if (keep) { deg++; if (r > 0.f) S += r; }
  }
  int s0 = WS_I(OFF_E0START)[dst], s1 = WS_I(OFF_E0START)[dst+1];
  deg += s1 - s0;
  int base = tid & 32;                  // shfl base of own 32-lane group
  for (int t = s0; t < s1; t++) {
    int src = WS_I(OFF_E0CSRS)[t];      // uniform within group
    float u;
    if (src < PN) {
      u = WS_F(OFF_UPATH)[src*32+f];
    } else {
      int jj = src - PN;
      float c0 = WS_F(OFF_CPOS)[2*jj], c1 = WS_F(OFF_CPOS)[2*jj+1];
      float clsv = (jj < NFREE) ? WS_F(OFF_CFREE)[f] : WS_F(OFF_CCOL)[f];
      float h = fmaf(c1, ncw1[32+f], fmaf(c0, ncw1[f], clsv));
      float xnf = fmaf((h - mean) * rstd, gamma[f], beta[f]);
      xnf = xnf > 0.f ? xnf : 0.f;
      float au = WS_F(OFF_BU)[f];
      #pragma unroll
      for (int m = 0; m < 32; m++)
        au = fmaf(__shfl(xnf, base + m), WS_F(OFF_WCU)[m*32+f], au);
      u = au;
    }
    float r = u + vf;
    if (r > 0.f) S += r;
  }
  // epilogue (LDS-staged 32x32 GEMVs)
  A[g][f] = S;  __syncthreads();
  float o = (float)deg * m0b2[f];
  #pragma unroll
  for (int k = 0; k < 32; k++) o = fmaf(A[g][k], m0w2[k*32+f], o);
  B[g][f] = o;  __syncthreads();
  float t1 = m1b1[f];
  #pragma unroll
  for (int k = 0; k < 32; k++) t1 = fmaf(B[g][k], m1w1[k*32+f], t1);
  t1 = t1 > 0.f ? t1 : 0.f;
  A[g][f] = t1; __syncthreads();
  float g2 = m1b2[f];
  #pragma unroll
  for (int k = 0; k < 32; k++) g2 = fmaf(A[g][k], m1w2[k*32+f], g2);
  float p0 = WS_F(OFF_PATH)[2*dst], p1 = WS_F(OFF_PATH)[2*dst+1];
  float hD = fmaf(p1, ncw1[32+f], fmaf(p0, ncw1[f], WS_F(OFF_CPATH)[f]));
  float xnd = fmaf((hD - mean) * rstd, gamma[f], beta[f]);
  xnd = xnd > 0.f ? xnd : 0.f;
  B[g][f] = xnd; __syncthreads();
  float x = ncb2[f];
  #pragma unroll
  for (int k = 0; k < 32; k++) x = fmaf(B[g][k], ncw2[k*32+f], x);
  float hh = x + g2;
  float r0 = hh * snw[2*f], r1 = hh * snw[2*f+1];
  #pragma unroll
  for (int off = 16; off >= 1; off >>= 1) {
    r0 += __shfl_xor(r0, off);
    r1 += __shfl_xor(r1, off);
  }
  if (f == 0) {
    float np0, np1;
    if (dst == 0 || dst == PN-1) { np0 = p0; np1 = p1; }
    else { np0 = snb[0] + r0; np1 = snb[1] + r1; }
    WS_F(OFF_PATH)[2*dst]   = np0;
    WS_F(OFF_PATH)[2*dst+1] = np1;
    outp[2*dst]   = np0;
    outp[2*dst+1] = np1;
  }
}

// ---------------- host launch ----------------

extern "C" void kernel_launch(void* const* d_in, const int* in_sizes, int n_in,
                              void* d_out, int out_size, void* d_ws, size_t ws_size,
                              hipStream_t stream) {
  const float* path  = (const float*)d_in[0];
  const float* freep = (const float*)d_in[1];
  const float* collp = (const float*)d_in[2];
  const int*   ei    = (const int*)d_in[4];
  const float* ncw1  = (const float*)d_in[6];
  const float* ncb1  = (const float*)d_in[7];
  const float* gamma = (const float*)d_in[8];
  const float* beta  = (const float*)d_in[9];
  const float* ncw2  = (const float*)d_in[10];
  const float* ncb2  = (const float*)d_in[11];
  const float* m0w1  = (const float*)d_in[12];
  const float* m0b1  = (const float*)d_in[13];
  const float* m0w2  = (const float*)d_in[14];
  const float* m0b2  = (const float*)d_in[15];
  const float* m1w1  = (const float*)d_in[16];
  const float* m1b1  = (const float*)d_in[17];
  const float* m1w2  = (const float*)d_in[18];
  const float* m1b2  = (const float*)d_in[19];
  const float* snw   = (const float*)d_in[20];
  const float* snb   = (const float*)d_in[21];
  char* ws = (char*)d_ws;

  k_init0  <<<64, 256, 0, stream>>>(ws, path);
  k_setupA <<<NCB + NEB + 1, 256, 0, stream>>>(ws, freep, collp, ei,
                                               ncw1, ncb1, m0w1, m0b1, ncw2, ncb2);
  k_setupB <<<NCB + 1, 256, 0, stream>>>(ws);
  k_scan   <<<1, 256, 0, stream>>>(ws);
  k_scatter<<<NCB, 256, 0, stream>>>(ws);

  for (int l = 0; l < NLOOP; l++) {
    k_A  <<<PN/4 + 64, 256, 0, stream>>>(ws, ncw1, gamma, beta);
    k_BC <<<64, 256, 0, stream>>>(ws, ncw1, gamma, beta, ncw2, ncb2,
                                  m0w2, m0b2, m1w1, m1b1, m1w2, m1b2,
                                  snw, snb, (float*)d_out);
  }
}

// Round 9
// 369.275 us; speedup vs baseline: 4.7120x; 1.0214x over previous
//
#include <hip/hip_runtime.h>
#include <stdint.h>

// Problem constants (fixed by setup_inputs)
#define PN     512
#define NFREE  50000
#define NCND   100000
#define NNODE  100512
#define NEDGE  300000
#define KK     10
#define NLOOP  5
#define EPSV   1e-5f

#define GRID   128
#define NCELL  (GRID*GRID)

// fixed spatial-hash bounds: candidates ~N(0,1); clamping keeps exactness
#define XMINF  (-6.f)
#define YMINF  (-6.f)
#define SPANF  12.f
#define IVCW   ((float)GRID / SPANF)
#define CWMIN  (SPANF / (float)GRID)

#define HSIZE  8192
#define HMASK  (HSIZE-1)
#define E0CAP  4096
#define EMPTYK 0xFFFFFFFFFFFFFFFFull

#define NCB    ((NCND+255)/256)    // 391
#define NEB    ((NEDGE+255)/256)   // 1172

// workspace layout (bytes) — ~3.2 MB
#define OFF_HASH    ((size_t)0)
#define OFF_CPOS    (OFF_HASH    + (size_t)HSIZE*8)
#define OFF_CSQ     (OFF_CPOS    + 800000)
#define OFF_SCND    (OFF_CSQ     + 400000)               // float4/cand, cell-sorted
#define OFF_CSTART  (OFF_SCND    + 1600000)              // NCELL+1 ints
#define OFF_COFS    (OFF_CSTART  + 65600)
#define OFF_MOM     (OFF_COFS    + 65600)                // 10 floats (F/C moments)
#define OFF_WCU     (OFF_MOM     + 64)
#define OFF_WCV     (OFF_WCU     + 4096)
#define OFF_BU      (OFF_WCV     + 4096)
#define OFF_BV      (OFF_BU      + 128)
#define OFF_CPATH   (OFF_BV      + 128)
#define OFF_CFREE   (OFF_CPATH   + 128)
#define OFF_CCOL    (OFF_CFREE   + 128)
#define OFF_PATH    (OFF_CCOL    + 128)                  // 16-aligned
#define OFF_E0S     (OFF_PATH    + 4096)
#define OFF_E0D     (OFF_E0S     + (size_t)E0CAP*4)
#define OFF_DEG0    (OFF_E0D     + (size_t)E0CAP*4)
#define OFF_E0C     (OFF_DEG0    + 2048)
#define OFF_E0START (OFF_E0C     + 64)                   // 513 ints (pad 2112)
#define OFF_E0OFS   (OFF_E0START + 2112)
#define OFF_E0CSRS  (OFF_E0OFS   + 2048)                 // E0CAP ints

#define WS_F(o)  ((float*)(ws + (o)))
#define WS_I(o)  ((int*)(ws + (o)))
#define WS_H(o)  ((unsigned long long*)(ws + (o)))

__device__ __forceinline__ bool lexless(float da, int ia, float db, int ib) {
  return (da < db) || (da == db && ia < ib);
}

__device__ __forceinline__ uint32_t hslot(unsigned long long key) {
  return (uint32_t)((key * 0x9E3779B97F4A7C15ull) >> 40) & HMASK;
}

// BN mean/rstd from analytic moments (cand moments in MOM + path moments pm*)
__device__ __forceinline__ void bn_from_moments(const char* ws,
    float w0, float w1, float cp, float clsF, float clsC,
    float pm0, float pm1, float pm00, float pm11, float pm01,
    float* meano, float* rstdo) {
  const float* M = (const float*)(ws + OFF_MOM);
  float sF0=M[0], sF1=M[1], sF00=M[2], sF11=M[3], sF01=M[4];
  float sC0=M[5], sC1=M[6], sC00=M[7], sC11=M[8], sC01=M[9];
  const float NC = (float)(NCND - NFREE);
  float sh  = w0*(sF0+sC0+pm0) + w1*(sF1+sC1+pm1)
            + (float)NFREE*clsF + NC*clsC + (float)PN*cp;
  float sh2 = w0*w0*(sF00+sC00+pm00) + w1*w1*(sF11+sC11+pm11)
            + 2.f*w0*w1*(sF01+sC01+pm01)
            + 2.f*w0*(clsF*sF0 + clsC*sC0 + cp*pm0)
            + 2.f*w1*(clsF*sF1 + clsC*sC1 + cp*pm1)
            + (float)NFREE*clsF*clsF + NC*clsC*clsC + (float)PN*cp*cp;
  float mean = sh  * (1.f / NNODE);
  float ex2  = sh2 * (1.f / NNODE);
  float var  = ex2 - mean * mean;
  *meano = mean;
  *rstdo = 1.0f / sqrtf(var + EPSV);
}

#define INSERT10(d2v, jv)                                                  \
  if (lexless((d2v), (jv), bd[9], bi[9])) {                                \
    bool placed = false;                                                   \
    _Pragma("unroll")                                                      \
    for (int k = 9; k > 0; k--) {                                          \
      bool shift = !placed && lexless((d2v), (jv), bd[k-1], bi[k-1]);      \
      bool here  = !placed && !shift;                                      \
      if (here)       { bd[k] = (d2v); bi[k] = (jv); placed = true; }      \
      else if (shift) { bd[k] = bd[k-1]; bi[k] = bi[k-1]; }                \
    }                                                                      \
    if (!placed) { bd[0] = (d2v); bi[0] = (jv); }                          \
  }

#define MERGEPOP() do {                                                    \
    float cd[10]; int ci[10];                                              \
    _Pragma("unroll")                                                      \
    for (int k = 0; k < 10; k++) { cd[k] = bd[k]; ci[k] = bi[k]; }         \
    _Pragma("unroll")                                                      \
    for (int r = 0; r < 10; r++) {                                         \
      float md = cd[0]; int mi = ci[0];                                    \
      _Pragma("unroll")                                                    \
      for (int off = 32; off >= 1; off >>= 1) {                            \
        float od = __shfl_xor(md, off);                                    \
        int   oi = __shfl_xor(mi, off);                                    \
        if (lexless(od, oi, md, mi)) { md = od; mi = oi; }                 \
      }                                                                    \
      bool win = (cd[0] == md) && (ci[0] == mi);                           \
      if (win) {                                                           \
        _Pragma("unroll")                                                  \
        for (int k = 0; k < 9; k++) { cd[k] = cd[k+1]; ci[k] = ci[k+1]; }  \
        cd[9] = 3.4e38f; ci[9] = 0x7FFFFFFF;                               \
      }                                                                    \
      if (lane == r) selIdx = mi;                                          \
      cur10d = md;                                                         \
    }                                                                      \
  } while (0)

#define SCAN_BOX(xA, xB, yA, yB) do {                                      \
    for (int _y = (yA); _y <= (yB); _y++) {                                \
      int _s = cst[_y*GRID + (xA)], _e = cst[_y*GRID + (xB) + 1];          \
      for (int _t = _s + lane; _t < _e; _t += 64) {                        \
        float4 _q = scnd[_t];                                              \
        float _d2 = (psq + _q.z) - 2.f * fmaf(p1, _q.y, p0 * _q.x);        \
        int _j = __float_as_int(_q.w);                                     \
        INSERT10(_d2, _j);                                                 \
      }                                                                    \
    }                                                                      \
  } while (0)

// ---------------- setup kernels ----------------

__global__ __launch_bounds__(256) void k_init0(char* __restrict__ ws,
                                               const float* __restrict__ path_in) {
  unsigned i = blockIdx.x * 256u + threadIdx.x;       // grid = 65 → 16640 ids
  if (i < HSIZE)   WS_H(OFF_HASH)[i] = EMPTYK;
  if (i < NCELL+1) WS_I(OFF_CSTART)[i] = 0;
  if (i < 1024)    WS_F(OFF_PATH)[i] = path_in[i];
  if (i < 512)     WS_I(OFF_DEG0)[i] = 0;
  if (i < 16)      WS_F(OFF_MOM)[i] = 0.f;
  if (i == 0)      *WS_I(OFF_E0C) = 0;
}

// roles: b<NCB cand(pos/norm/moments/hist) | b<NCB+NEB edge filter+dedup | last wprep
__global__ __launch_bounds__(256) void k_setupA(char* __restrict__ ws,
    const float* __restrict__ freep, const float* __restrict__ collp,
    const int* __restrict__ ei,
    const float* __restrict__ ncw1, const float* __restrict__ ncb1,
    const float* __restrict__ m0w1, const float* __restrict__ m0b1,
    const float* __restrict__ ncw2, const float* __restrict__ ncb2) {
  int b = blockIdx.x, tid = threadIdx.x;
  if (b < NCB) {
    __shared__ float s10[4][10];
    int j = b*256 + tid;
    bool valid = (j < NCND);
    float c0 = 0.f, c1 = 0.f;
    if (valid) {
      if (j < NFREE) { c0 = freep[2*j];          c1 = freep[2*j+1]; }
      else           { c0 = collp[2*(j-NFREE)];  c1 = collp[2*(j-NFREE)+1]; }
      ((float2*)(ws + OFF_CPOS))[j] = make_float2(c0, c1);
      WS_F(OFF_CSQ)[j] = c0*c0 + c1*c1;
    }
    bool isF = valid && (j < NFREE), isC = valid && (j >= NFREE);
    float v[10];
    v[0]=isF?c0:0.f; v[1]=isF?c1:0.f; v[2]=isF?c0*c0:0.f; v[3]=isF?c1*c1:0.f; v[4]=isF?c0*c1:0.f;
    v[5]=isC?c0:0.f; v[6]=isC?c1:0.f; v[7]=isC?c0*c0:0.f; v[8]=isC?c1*c1:0.f; v[9]=isC?c0*c1:0.f;
    #pragma unroll
    for (int q = 0; q < 10; q++)
      #pragma unroll
      for (int off = 32; off >= 1; off >>= 1) v[q] += __shfl_xor(v[q], off);
    int wv = tid >> 6, lane = tid & 63;
    if (lane == 0) {
      #pragma unroll
      for (int q = 0; q < 10; q++) s10[wv][q] = v[q];
    }
    // histogram with fixed bbox (clamped — exactness preserved by phase C)
    if (valid) {
      int cx = min(GRID-1, max(0, (int)((c0 - XMINF) * IVCW)));
      int cy = min(GRID-1, max(0, (int)((c1 - YMINF) * IVCW)));
      atomicAdd(&WS_I(OFF_CSTART)[cy*GRID + cx], 1);
    }
    __syncthreads();
    if (tid < 10)
      atomicAdd(&WS_F(OFF_MOM)[tid], s10[0][tid]+s10[1][tid]+s10[2][tid]+s10[3][tid]);
  } else if (b < NCB + NEB) {
    int e = (b - NCB)*256 + tid;
    if (e >= NEDGE) return;
    int src = ei[e], dst = ei[NEDGE + e];
    if (dst >= PN) return;                         // only dst<PN edges matter
    unsigned long long key = (unsigned long long)src * NNODE + (unsigned long long)dst;
    unsigned long long* hash = WS_H(OFF_HASH);
    uint32_t slot = hslot(key);
    for (;;) {
      unsigned long long prev = atomicCAS(&hash[slot], EMPTYK, key);
      if (prev == EMPTYK) {
        int pos = atomicAdd(WS_I(OFF_E0C), 1);
        if (pos < E0CAP) {
          WS_I(OFF_E0S)[pos] = src;
          WS_I(OFF_E0D)[pos] = dst;
          atomicAdd(&WS_I(OFF_DEG0)[dst], 1);
        }
        break;
      }
      if (prev == key) break;
      slot = (slot + 1) & HMASK;
    }
  } else {
    __shared__ float Wu[1024], Wv[1024];
    for (int it = 0; it < 4; it++) {
      int idx = it*256 + tid, k = idx >> 5, g = idx & 31;
      float a = m0w1[k*32+g], b2 = m0w1[(k+32)*32+g], c = m0w1[(k+64)*32+g];
      Wu[idx] = a + b2;  Wv[idx] = c - a;
    }
    __syncthreads();
    for (int it = 0; it < 4; it++) {
      int idx = it*256 + tid, k = idx >> 5, g = idx & 31;
      float au = 0.f, av = 0.f;
      #pragma unroll
      for (int f = 0; f < 32; f++) {
        float w2 = ncw2[k*32+f];
        au = fmaf(w2, Wu[f*32+g], au);
        av = fmaf(w2, Wv[f*32+g], av);
      }
      WS_F(OFF_WCU)[idx] = au;  WS_F(OFF_WCV)[idx] = av;
    }
    if (tid < 32) {
      float bu = 0.f, bv = 0.f;
      #pragma unroll
      for (int f = 0; f < 32; f++) {
        bu = fmaf(ncb2[f], Wu[f*32+tid], bu);
        bv = fmaf(ncb2[f], Wv[f*32+tid], bv);
      }
      WS_F(OFF_BU)[tid] = bu;
      WS_F(OFF_BV)[tid] = bv + m0b1[tid];        // fold mp0_b1 into dst-side
      WS_F(OFF_CPATH)[tid] = ncw1[64+tid]  + ncb1[tid];
      WS_F(OFF_CFREE)[tid] = ncw1[96+tid]  + ncb1[tid];
      WS_F(OFF_CCOL)[tid]  = ncw1[128+tid] + ncb1[tid];
    }
  }
}

// b==0: exclusive scan of cell counts | b==1: CSR build of fixed edges
__global__ __launch_bounds__(256) void k_scan2(char* __restrict__ ws) {
  int b = blockIdx.x, tid = threadIdx.x;
  if (b == 0) {
    __shared__ int part[256];
    int* cnt = WS_I(OFF_CSTART);
    int base = tid * (NCELL/256);
    int sum = 0;
    for (int k = 0; k < NCELL/256; k++) sum += cnt[base+k];
    part[tid] = sum;
    __syncthreads();
    for (int off = 1; off < 256; off <<= 1) {
      int t = (tid >= off) ? part[tid - off] : 0;
      __syncthreads();
      part[tid] += t;
      __syncthreads();
    }
    int run = part[tid] - sum;
    for (int k = 0; k < NCELL/256; k++) {
      int c = cnt[base+k];
      cnt[base+k] = run;
      WS_I(OFF_COFS)[base+k] = run;
      run += c;
    }
    if (tid == 255) cnt[NCELL] = run;
  } else {
    __shared__ int sc[512];
    sc[tid]     = WS_I(OFF_DEG0)[tid];
    sc[256+tid] = WS_I(OFF_DEG0)[256+tid];
    __syncthreads();
    if (tid == 0) {
      int run = 0;
      for (int i = 0; i < 512; i++) { int c = sc[i]; sc[i] = run; run += c; }
      WS_I(OFF_E0START)[512] = run;
    }
    __syncthreads();
    WS_I(OFF_E0START)[tid]     = sc[tid];
    WS_I(OFF_E0START)[256+tid] = sc[256+tid];
    WS_I(OFF_E0OFS)[tid]       = sc[tid];
    WS_I(OFF_E0OFS)[256+tid]   = sc[256+tid];
    __syncthreads();
    int n = *WS_I(OFF_E0C); if (n > E0CAP) n = E0CAP;
    for (int e = tid; e < n; e += 256) {
      int dst = WS_I(OFF_E0D)[e];
      int pos = atomicAdd(&WS_I(OFF_E0OFS)[dst], 1);
      WS_I(OFF_E0CSRS)[pos] = WS_I(OFF_E0S)[e];
    }
  }
}

__global__ __launch_bounds__(256) void k_scatter(char* __restrict__ ws) {
  int j = blockIdx.x * 256 + threadIdx.x;
  if (j >= NCND) return;
  float2 c = ((const float2*)(ws + OFF_CPOS))[j];
  int cx = min(GRID-1, max(0, (int)((c.x - XMINF) * IVCW)));
  int cy = min(GRID-1, max(0, (int)((c.y - YMINF) * IVCW)));
  int pos = atomicAdd(&WS_I(OFF_COFS)[cy*GRID + cx], 1);
  ((float4*)(ws + OFF_SCND))[pos] =
      make_float4(c.x, c.y, WS_F(OFF_CSQ)[j], __int_as_float(j));
}

// ---------------- the fused per-loop kernel ----------------
// 128 blocks x 256 threads; one WAVE per path node dst. Everything in-wave:
// kNN -> keep mask -> analytic BN -> v[dst], u[srcs] (shfl-dots) -> S ->
// epilogue GEMVs (shfl-dots) -> path/out write. No cross-block dependency
// inside the dispatch; loop-carried path update crosses dispatch boundaries.
__global__ __launch_bounds__(256) void k_loop(char* __restrict__ ws,
    const float* __restrict__ ncw1, const float* __restrict__ gamma,
    const float* __restrict__ beta, const float* __restrict__ ncw2,
    const float* __restrict__ ncb2, const float* __restrict__ m0w2,
    const float* __restrict__ m0b2, const float* __restrict__ m1w1,
    const float* __restrict__ m1b1, const float* __restrict__ m1w2,
    const float* __restrict__ m1b2, const float* __restrict__ snw,
    const float* __restrict__ snb, float* __restrict__ outp) {
  int tid = threadIdx.x, lane = tid & 63;
  int node = blockIdx.x*4 + (tid >> 6);
  float* pathb = WS_F(OFF_PATH);
  const float4* scnd = (const float4*)(ws + OFF_SCND);
  const int* cst = WS_I(OFF_CSTART);

  float p0 = pathb[2*node], p1 = pathb[2*node+1];
  float psq = p0*p0 + p1*p1;
  int cx = min(GRID-1, max(0, (int)((p0 - XMINF) * IVCW)));
  int cy = min(GRID-1, max(0, (int)((p1 - YMINF) * IVCW)));

  // ---- kNN phase A: grow square box until >=10 pts (prefix counts) ----
  int R = 1, xL, xR, yL, yR;
  for (;;) {
    xL = max(cx - R, 0); xR = min(cx + R, GRID-1);
    yL = max(cy - R, 0); yR = min(cy + R, GRID-1);
    int cnt = 0;
    for (int y = yL + lane; y <= yR; y += 64)
      cnt += cst[y*GRID + xR + 1] - cst[y*GRID + xL];
    #pragma unroll
    for (int off = 32; off >= 1; off >>= 1) cnt += __shfl_xor(cnt, off);
    if (cnt >= KK || R >= GRID) break;
    R <<= 1;
  }

  float bd[10]; int bi[10];
  #pragma unroll
  for (int k = 0; k < 10; k++) { bd[k] = 3.4e38f; bi[k] = 0x7FFFFFFF; }
  float cur10d = 3.4e38f;
  int selIdx = 0x7FFFFFFF;

  // ---- phase B: seed box scan (coalesced row spans) ----
  SCAN_BOX(xL, xR, yL, yR);
  MERGEPOP();

  // ---- phase C: exact re-scan of cells overlapping [p +- r] ----
  float r = sqrtf(cur10d) * 1.000002f;
  int xL2 = min(GRID-1, max(0, (int)((p0 - r - XMINF) * IVCW)));
  int xR2 = min(GRID-1, max(0, (int)((p0 + r - XMINF) * IVCW)));
  int yL2 = min(GRID-1, max(0, (int)((p1 - r - YMINF) * IVCW)));
  int yR2 = min(GRID-1, max(0, (int)((p1 + r - YMINF) * IVCW)));
  #pragma unroll
  for (int k = 0; k < 10; k++) { bd[k] = 3.4e38f; bi[k] = 0x7FFFFFFF; }
  SCAN_BOX(xL2, xR2, yL2, yR2);
  MERGEPOP();

  // ---- dedup vs fixed edges (tiny CSR); ballot -> wave-uniform keep mask ----
  int s0 = WS_I(OFF_E0START)[node], s1 = WS_I(OFF_E0START)[node+1];
  int keep = 0;
  if (lane < KK) {
    int srcg = selIdx + PN;
    keep = 1;
    for (int t = s0; t < s1; t++)
      if (WS_I(OFF_E0CSRS)[t] == srcg) { keep = 0; break; }
  }
  unsigned long long kmask = __ballot(keep);
  int deg = (int)__popcll(kmask) + (s1 - s0);

  // ---- analytic BN (per-feature; lanes 32..63 mirror features 0..31) ----
  int fA = lane & 31;
  float w0 = ncw1[fA], w1 = ncw1[32+fA], cp = WS_F(OFF_CPATH)[fA];
  float clsF = WS_F(OFF_CFREE)[fA], clsC = WS_F(OFF_CCOL)[fA];
  float pm0=0,pm1=0,pm00=0,pm11=0,pm01=0;
  for (int r2 = lane; r2 < PN; r2 += 64) {
    float q0 = pathb[2*r2], q1 = pathb[2*r2+1];
    pm0+=q0; pm1+=q1; pm00+=q0*q0; pm11+=q1*q1; pm01+=q0*q1;
  }
  #pragma unroll
  for (int off = 32; off >= 1; off >>= 1) {
    pm0+=__shfl_xor(pm0,off); pm1+=__shfl_xor(pm1,off); pm00+=__shfl_xor(pm00,off);
    pm11+=__shfl_xor(pm11,off); pm01+=__shfl_xor(pm01,off);
  }
  float mean, rstd;
  bn_from_moments(ws, w0, w1, cp, clsF, clsC, pm0, pm1, pm00, pm11, pm01, &mean, &rstd);
  float gm = gamma[fA], bt = beta[fA];
  const float* wcu = WS_F(OFF_WCU); const float* wcv = WS_F(OFF_WCV);
  float buf = WS_F(OFF_BU)[fA];

  // ---- xn_dst and v[dst] ----
  float hD = fmaf(p1, w1, fmaf(p0, w0, cp));
  float xnd = fmaf((hD - mean) * rstd, gm, bt);
  xnd = xnd > 0.f ? xnd : 0.f;
  float av = WS_F(OFF_BV)[fA];
  #pragma unroll
  for (int m = 0; m < 32; m++) av = fmaf(__shfl(xnd, m), wcv[m*32+fA], av);

  // ---- S: kept kNN edges ----
  float S = 0.f;
  for (int k = 0; k < KK; k++) {
    if (!((kmask >> k) & 1ull)) continue;          // wave-uniform
    int jj = __shfl(selIdx, k);
    float c0 = WS_F(OFF_CPOS)[2*jj], c1 = WS_F(OFF_CPOS)[2*jj+1];
    float clsv = (jj < NFREE) ? clsF : clsC;
    float h = fmaf(c1, w1, fmaf(c0, w0, clsv));
    float xnf = fmaf((h - mean) * rstd, gm, bt);
    xnf = xnf > 0.f ? xnf : 0.f;
    float au = buf;
    #pragma unroll
    for (int m = 0; m < 32; m++) au = fmaf(__shfl(xnf, m), wcu[m*32+fA], au);
    float rr = au + av;
    if (rr > 0.f) S += rr;
  }
  // ---- S: fixed edges (src may be path node or candidate) ----
  for (int t = s0; t < s1; t++) {
    int src = WS_I(OFF_E0CSRS)[t];                 // wave-uniform
    float q0, q1, clsv;
    if (src < PN) { q0 = pathb[2*src]; q1 = pathb[2*src+1]; clsv = cp; }
    else {
      int jj = src - PN;
      q0 = WS_F(OFF_CPOS)[2*jj]; q1 = WS_F(OFF_CPOS)[2*jj+1];
      clsv = (jj < NFREE) ? clsF : clsC;
    }
    float h = fmaf(q1, w1, fmaf(q0, w0, clsv));
    float xnf = fmaf((h - mean) * rstd, gm, bt);
    xnf = xnf > 0.f ? xnf : 0.f;
    float au = buf;
    #pragma unroll
    for (int m = 0; m < 32; m++) au = fmaf(__shfl(xnf, m), wcu[m*32+fA], au);
    float rr = au + av;
    if (rr > 0.f) S += rr;
  }

  // ---- epilogue: four 32x32 GEMVs via shfl-dots ----
  float o = (float)deg * m0b2[fA];
  #pragma unroll
  for (int k = 0; k < 32; k++) o = fmaf(__shfl(S, k), m0w2[k*32+fA], o);
  float t1 = m1b1[fA];
  #pragma unroll
  for (int k = 0; k < 32; k++) t1 = fmaf(__shfl(o, k), m1w1[k*32+fA], t1);
  t1 = t1 > 0.f ? t1 : 0.f;
  float g2 = m1b2[fA];
  #pragma unroll
  for (int k = 0; k < 32; k++) g2 = fmaf(__shfl(t1, k), m1w2[k*32+fA], g2);
  float x = ncb2[fA];
  #pragma unroll
  for (int k = 0; k < 32; k++) x = fmaf(__shfl(xnd, k), ncw2[k*32+fA], x);
  float hh = x + g2;
  float r0 = hh * snw[2*fA], r1 = hh * snw[2*fA+1];
  #pragma unroll
  for (int off = 16; off >= 1; off >>= 1) {
    r0 += __shfl_xor(r0, off);
    r1 += __shfl_xor(r1, off);
  }
  if (lane == 0) {
    float np0, np1;
    if (node == 0 || node == PN-1) { np0 = p0; np1 = p1; }  // endpoints fixed
    else { np0 = snb[0] + r0; np1 = snb[1] + r1; }
    pathb[2*node]   = np0;
    pathb[2*node+1] = np1;
    outp[2*node]   = np0;
    outp[2*node+1] = np1;
  }
}

// ---------------- host launch ----------------

extern "C" void kernel_launch(void* const* d_in, const int* in_sizes, int n_in,
                              void* d_out, int out_size, void* d_ws, size_t ws_size,
                              hipStream_t stream) {
  const float* path  = (const float*)d_in[0];
  const float* freep = (const float*)d_in[1];
  const float* collp = (const float*)d_in[2];
  const int*   ei    = (const int*)d_in[4];
  const float* ncw1  = (const float*)d_in[6];
  const float* ncb1  = (const float*)d_in[7];
  const float* gamma = (const float*)d_in[8];
  const float* beta  = (const float*)d_in[9];
  const float* ncw2  = (const float*)d_in[10];
  const float* ncb2  = (const float*)d_in[11];
  const float* m0w1  = (const float*)d_in[12];
  const float* m0b1  = (const float*)d_in[13];
  const float* m0w2  = (const float*)d_in[14];
  const float* m0b2  = (const float*)d_in[15];
  const float* m1w1  = (const float*)d_in[16];
  const float* m1b1  = (const float*)d_in[17];
  const float* m1w2  = (const float*)d_in[18];
  const float* m1b2  = (const float*)d_in[19];
  const float* snw   = (const float*)d_in[20];
  const float* snb   = (const float*)d_in[21];
  char* ws = (char*)d_ws;

  k_init0  <<<65, 256, 0, stream>>>(ws, path);
  k_setupA <<<NCB + NEB + 1, 256, 0, stream>>>(ws, freep, collp, ei,
                                               ncw1, ncb1, m0w1, m0b1, ncw2, ncb2);
  k_scan2  <<<2, 256, 0, stream>>>(ws);
  k_scatter<<<NCB, 256, 0, stream>>>(ws);

  for (int l = 0; l < NLOOP; l++) {
    k_loop<<<PN/4, 256, 0, stream>>>(ws, ncw1, gamma, beta, ncw2, ncb2,
                                     m0w2, m0b2, m1w1, m1b1, m1w2, m1b2,
                                     snw, snb, (float*)d_out);
  }
}